// Round 3
// baseline (2120.745 us; speedup 1.0000x reference)
//
#include <hip/hip_runtime.h>

#define NPTS 8192
#define KNN  128
#define TPB  256

// ============ LAPACK-faithful 3x3 ssyevd (lower), FLOAT32, BLAS-ref op order ============

__device__ __forceinline__ float f_signf(float a, float b){ return copysignf(a, b); }

__device__ float lapy2f(float x, float y){
#pragma clang fp contract(off)
  float xa = fabsf(x), ya = fabsf(y);
  float w = fmaxf(xa, ya), zz = fminf(xa, ya);
  if (zz == 0.0f) return w;
  float t = zz / w;
  return w * sqrtf(1.0f + t * t);
}

__device__ void slartg_(float f, float g, float &c, float &s, float &r){
#pragma clang fp contract(off)
  const float safmin = 1.17549435e-38f;
  const float safmax = 8.5070592e37f;      // 1/safmin
  if (g == 0.0f){ c = 1.0f; s = 0.0f; r = f; }
  else if (f == 0.0f){ c = 0.0f; s = f_signf(1.0f, g); r = fabsf(g); }
  else {
    float f1 = fabsf(f), g1 = fabsf(g);
    float rtmin = sqrtf(safmin);
    float rtmax = sqrtf(safmax * 0.5f);
    if (f1 > rtmin && f1 < rtmax && g1 > rtmin && g1 < rtmax){
      float d = sqrtf(f * f + g * g);
      float p = 1.0f / d;
      c = f1 * p;
      s = g * f_signf(p, f);
      r = f_signf(d, f);
    } else {
      float u = fminf(safmax, fmaxf(safmin, fmaxf(f1, g1)));
      float uu = 1.0f / u;
      float fs = f * uu, gs = g * uu;
      float d = sqrtf(fs * fs + gs * gs);
      float p = 1.0f / d;
      c = fabsf(fs) * p;
      s = gs * f_signf(p, f);
      r = f_signf(d, f) * u;
    }
  }
}

__device__ void slaev2_(float a, float b, float cc, float &rt1, float &rt2,
                        float &cs1, float &sn1){
#pragma clang fp contract(off)
  float sm = a + cc;
  float df = a - cc;
  float adf = fabsf(df);
  float tb = b + b;
  float ab = fabsf(tb);
  float acmx, acmn;
  if (fabsf(a) > fabsf(cc)){ acmx = a; acmn = cc; } else { acmx = cc; acmn = a; }
  float rt;
  if (adf > ab){ float t = ab / adf; rt = adf * sqrtf(1.0f + t * t); }
  else if (adf < ab){ float t = adf / ab; rt = ab * sqrtf(1.0f + t * t); }
  else { rt = ab * sqrtf(2.0f); }
  int sgn1;
  if (sm < 0.0f){ rt1 = 0.5f * (sm - rt); sgn1 = -1; rt2 = (acmx / rt1) * acmn - (b / rt1) * b; }
  else if (sm > 0.0f){ rt1 = 0.5f * (sm + rt); sgn1 = 1; rt2 = (acmx / rt1) * acmn - (b / rt1) * b; }
  else { rt1 = 0.5f * rt; rt2 = -0.5f * rt; sgn1 = 1; }
  float cs; int sgn2;
  if (df >= 0.0f){ cs = df + rt; sgn2 = 1; }
  else { cs = df - rt; sgn2 = -1; }
  float acs = fabsf(cs);
  if (acs > ab){
    float ct = -tb / cs;
    sn1 = 1.0f / sqrtf(1.0f + ct * ct);
    cs1 = ct * sn1;
  } else {
    if (ab == 0.0f){ cs1 = 1.0f; sn1 = 0.0f; }
    else {
      float tn = -cs / tb;
      cs1 = 1.0f / sqrtf(1.0f + tn * tn);
      sn1 = tn * cs1;
    }
  }
  if (sgn1 == sgn2){ float tn = cs1; cs1 = -sn1; sn1 = tn; }
}

__device__ void ssteqr3(float *d, float *e, float z[3][3]){
#pragma clang fp contract(off)
  const float eps  = 5.9604645e-8f;     // 2^-24
  const float eps2 = 3.5527137e-15f;    // 2^-48
  const float safmin = 1.17549435e-38f;
  const int n = 3;
  for (int i = 0; i < 3; i++)
    for (int j = 0; j < 3; j++) z[i][j] = (i == j) ? 1.0f : 0.0f;
  const int nmaxit = n * 30;
  int jtot = 0;
  int l1 = 1;
  int l = 0, lsv = 0, lend = 0, lendsv = 0, m = 0;
  float p, g, r, c, s, f, b;
  float csave[2], ssave[2];
  int safety = 0;

L10:
  if (++safety > 64) goto L190;
  if (l1 > n) goto L160;
  if (l1 > 1) e[l1 - 2] = 0.0f;
  if (l1 <= n - 1){
    for (m = l1; m <= n - 1; m++){
      float tst = fabsf(e[m - 1]);
      if (tst == 0.0f) goto L30;
      if (tst <= (sqrtf(fabsf(d[m - 1])) * sqrtf(fabsf(d[m]))) * eps){ e[m - 1] = 0.0f; goto L30; }
    }
  }
  m = n;
L30:
  l = l1; lsv = l; lend = m; lendsv = lend; l1 = m + 1;
  if (lend == l) goto L10;
  {
    float anorm = fabsf(d[l - 1]);
    for (int q = l; q <= lend - 1; q++){
      anorm = fmaxf(anorm, fabsf(d[q]));
      anorm = fmaxf(anorm, fabsf(e[q - 1]));
    }
    if (anorm == 0.0f) goto L10;
  }
  if (fabsf(d[lend - 1]) < fabsf(d[l - 1])){ lend = lsv; l = lendsv; }
  if (lend > l){
    // QL
L40:
    if (l != lend){
      for (m = l; m <= lend - 1; m++){
        float tst = e[m - 1] * e[m - 1];
        if (tst <= (eps2 * fabsf(d[m - 1])) * fabsf(d[m]) + safmin) goto L60;
      }
    }
    m = lend;
L60:
    if (m < lend) e[m - 1] = 0.0f;
    p = d[l - 1];
    if (m == l) goto L80;
    if (m == l + 1){
      float rt1, rt2;
      slaev2_(d[l - 1], e[l - 1], d[l], rt1, rt2, c, s);
      for (int i2 = 0; i2 < 3; i2++){
        float temp = z[i2][l];
        z[i2][l]     = c * temp - s * z[i2][l - 1];
        z[i2][l - 1] = s * temp + c * z[i2][l - 1];
      }
      d[l - 1] = rt1; d[l] = rt2; e[l - 1] = 0.0f;
      l += 2;
      if (l <= lend) goto L40;
      goto L140;
    }
    if (jtot == nmaxit) goto L140;
    jtot++;
    g = (d[l] - p) / (2.0f * e[l - 1]);
    r = lapy2f(g, 1.0f);
    g = d[m - 1] - p + e[l - 1] / (g + f_signf(r, g));
    s = 1.0f; c = 1.0f; p = 0.0f;
    for (int i2 = m - 1; i2 >= l; i2--){
      f = s * e[i2 - 1];
      b = c * e[i2 - 1];
      slartg_(g, f, c, s, r);
      if (i2 != m - 1) e[i2] = r;
      g = d[i2] - p;
      r = (d[i2 - 1] - g) * s + 2.0f * c * b;
      p = s * r;
      d[i2] = g + p;
      g = c * r - b;
      csave[i2 - l] = c; ssave[i2 - l] = -s;
    }
    {
      int mmc = m - l + 1;
      for (int j2 = mmc - 1; j2 >= 1; j2--){
        float cj = csave[j2 - 1], sj = ssave[j2 - 1];
        if (cj != 1.0f || sj != 0.0f){
          for (int i2 = 0; i2 < 3; i2++){
            float temp = z[i2][(l - 1) + j2];
            z[i2][(l - 1) + j2]     = cj * temp - sj * z[i2][(l - 1) + j2 - 1];
            z[i2][(l - 1) + j2 - 1] = sj * temp + cj * z[i2][(l - 1) + j2 - 1];
          }
        }
      }
    }
    d[l - 1] -= p;
    e[l - 1] = g;
    goto L40;
L80:
    d[l - 1] = p;
    l++;
    if (l <= lend) goto L40;
    goto L140;
  } else {
    // QR
L90:
    if (l != lend){
      for (m = l; m >= lend + 1; m--){
        float tst = e[m - 2] * e[m - 2];
        if (tst <= (eps2 * fabsf(d[m - 1])) * fabsf(d[m - 2]) + safmin) goto L110;
      }
    }
    m = lend;
L110:
    if (m > lend) e[m - 2] = 0.0f;
    p = d[l - 1];
    if (m == l) goto L130;
    if (m == l - 1){
      float rt1, rt2;
      slaev2_(d[l - 2], e[l - 2], d[l - 1], rt1, rt2, c, s);
      for (int i2 = 0; i2 < 3; i2++){
        float temp = z[i2][l - 1];
        z[i2][l - 1] = c * temp - s * z[i2][l - 2];
        z[i2][l - 2] = s * temp + c * z[i2][l - 2];
      }
      d[l - 2] = rt1; d[l - 1] = rt2; e[l - 2] = 0.0f;
      l -= 2;
      if (l >= lend) goto L90;
      goto L140;
    }
    if (jtot == nmaxit) goto L140;
    jtot++;
    g = (d[l - 2] - p) / (2.0f * e[l - 2]);
    r = lapy2f(g, 1.0f);
    g = d[m - 1] - p + e[l - 2] / (g + f_signf(r, g));
    s = 1.0f; c = 1.0f; p = 0.0f;
    for (int i2 = m; i2 <= l - 1; i2++){
      f = s * e[i2 - 1];
      b = c * e[i2 - 1];
      slartg_(g, f, c, s, r);
      if (i2 != m) e[i2 - 2] = r;
      g = d[i2 - 1] - p;
      r = (d[i2] - g) * s + 2.0f * c * b;
      p = s * r;
      d[i2 - 1] = g + p;
      g = c * r - b;
      csave[i2 - m] = c; ssave[i2 - m] = s;
    }
    {
      int cnt = l - m + 1;
      for (int j2 = 1; j2 <= cnt - 1; j2++){
        float cj = csave[j2 - 1], sj = ssave[j2 - 1];
        if (cj != 1.0f || sj != 0.0f){
          for (int i2 = 0; i2 < 3; i2++){
            float temp = z[i2][(m - 1) + j2];
            z[i2][(m - 1) + j2]     = cj * temp - sj * z[i2][(m - 1) + j2 - 1];
            z[i2][(m - 1) + j2 - 1] = sj * temp + cj * z[i2][(m - 1) + j2 - 1];
          }
        }
      }
    }
    d[l - 1] -= p;
    e[l - 2] = g;
    goto L90;
L130:
    d[l - 1] = p;
    l--;
    if (l >= lend) goto L90;
    goto L140;
  }
L140:
  if (jtot < nmaxit) goto L10;
  goto L190;
L160:
  for (int ii = 2; ii <= n; ii++){
    int i2 = ii - 1, k2 = i2;
    float pp = d[i2 - 1];
    for (int j2 = ii; j2 <= n; j2++){
      if (d[j2 - 1] < pp){ k2 = j2; pp = d[j2 - 1]; }
    }
    if (k2 != i2){
      d[k2 - 1] = d[i2 - 1]; d[i2 - 1] = pp;
      for (int r2 = 0; r2 < 3; r2++){
        float tt = z[r2][i2 - 1]; z[r2][i2 - 1] = z[r2][k2 - 1]; z[r2][k2 - 1] = tt;
      }
    }
  }
L190: ;
}

// A6 = {a00,a10,a20,a11,a21,a22} (lower). Smallest-eigval eigenvector, LAPACK sign.
__device__ void eigh3_smallest_f32(const float A6[6], float zout[3]){
#pragma clang fp contract(off)
  float a00 = A6[0], a10 = A6[1], a20 = A6[2], a11 = A6[3], a21 = A6[4], a22 = A6[5];
  float d[3], e[2], tau1 = 0.0f, v2 = 0.0f;
  // SSYTD2 (lower), n=3, BLAS reference op order
  float xnorm = fabsf(a20);
  if (xnorm == 0.0f){
    tau1 = 0.0f;
    d[0] = a00; d[1] = a11; d[2] = a22; e[0] = a10; e[1] = a21;
  } else {
    float alpha = a10;
    float beta = -f_signf(lapy2f(alpha, xnorm), alpha);
    tau1 = (beta - alpha) / beta;
    float rsc = 1.0f / (alpha - beta);
    v2 = a20 * rsc;
    // SSYMV y = tau*A*v (reference loop order)
    float y1 = tau1 * a11 + tau1 * (a21 * v2);
    float y2 = tau1 * a21 + (tau1 * v2) * a22;
    // SDOT + scale
    float dotv = y1 + y2 * v2;
    float al = (-0.5f * tau1) * dotv;
    // SAXPY w = y + al*v
    float w1 = y1 + al;
    float w2 = y2 + al * v2;
    // SSYR2 A -= v w' + w v' (reference loop order)
    d[0] = a00;
    d[1] = (a11 + (-w1)) + (w1 * (-1.0f));
    e[1] = (a21 + v2 * (-w1)) + (w2 * (-1.0f));
    d[2] = (a22 + v2 * (-w2)) + (w2 * (-v2));
    e[0] = beta;
  }
  float z[3][3];
  ssteqr3(d, e, z);
  // SORMTR/SORMQR: Z := H1*Z on rows 2,3 (SLARF: gemv-T then ger)
  if (tau1 != 0.0f){
    for (int j = 0; j < 3; j++){
      float wj = z[1][j] + z[2][j] * v2;
      float tmp = (-tau1) * wj;
      z[1][j] = z[1][j] + tmp;
      z[2][j] = z[2][j] + v2 * tmp;
    }
  }
  zout[0] = z[0][0]; zout[1] = z[1][0]; zout[2] = z[2][0];
}

// ===================== phase 1 =====================
__global__ __launch_bounds__(TPB) void phase1_kernel(const float* __restrict__ verts,
                                                     float* __restrict__ normals,
                                                     unsigned short* __restrict__ idx_out)
{
#pragma clang fp contract(off)
  __shared__ unsigned long long keys[NPTS];   // 64 KiB combined (Dbits<<13|idx) keys
  __shared__ unsigned long long skey[KNN];
  __shared__ float nbx[KNN], nby[KNN], nbz[KNN], wv[KNN];
  __shared__ unsigned int bins[256];
  __shared__ unsigned long long sh_prefix;
  __shared__ unsigned int sh_kt, sh_cnt, sh_gcnt, sh_vote;
  __shared__ float sh_z[3];

  const int g   = blockIdx.x;
  const int smp = g >> 13;
  const int i   = g & (NPTS - 1);
  const int t   = threadIdx.x;
  const float* V = verts + (size_t)smp * NPTS * 3;

  const float vx = V[3 * i + 0], vy = V[3 * i + 1], vz = V[3 * i + 2];
  const float sqi = (vx * vx + vy * vy) + vz * vz;

  // f32 D per np formula: (sq_i - 2*dot) + sq_j, dot = OpenBLAS sgemm FMA chain
  for (int j = t; j < NPTS; j += TPB){
    float a = V[3 * j + 0], b = V[3 * j + 1], c = V[3 * j + 2];
    float dot = fmaf(vz, c, fmaf(vy, b, vx * a));
    float sqj = (a * a + b * b) + c * c;
    float d2 = (sqi - 2.0f * dot) + sqj;
    float D = sqrtf(fmaxf(d2, 1e-12f));
    keys[j] = (((unsigned long long)__float_as_uint(D)) << 13) | (unsigned long long)j;
  }
  __syncthreads();

  // radix-select kth smallest unique 44-bit key (6x8-bit levels, early exit)
  unsigned long long prefix = 0ULL;
  unsigned int ktarget = KNN;
  for (int level = 0; level < 6; level++){
    int shift = 40 - 8 * level;
    bins[t] = 0u;
    __syncthreads();
    for (int j = t; j < NPTS; j += TPB){
      unsigned long long kk = keys[j];
      if (level == 0 || (kk >> (shift + 8)) == (prefix >> (shift + 8)))
        atomicAdd(&bins[(unsigned)((kk >> shift) & 255ULL)], 1u);
    }
    __syncthreads();
    if (t == 0){
      unsigned int cum = 0; int selb = 255;
      for (int bq = 0; bq < 256; bq++){
        unsigned int cb = bins[bq];
        if (ktarget <= cum + cb){ selb = bq; break; }
        cum += cb;
      }
      sh_prefix = prefix | ((unsigned long long)selb << shift);
      sh_kt = ktarget - cum;
      sh_cnt = bins[selb];
    }
    __syncthreads();
    prefix = sh_prefix; ktarget = sh_kt;
    unsigned int cnt_in = sh_cnt;
    __syncthreads();
    if (cnt_in == 1u && level < 5){
      for (int j = t; j < NPTS; j += TPB){
        unsigned long long kk = keys[j];
        if ((kk >> shift) == (prefix >> shift)) sh_prefix = kk;  // unique
      }
      __syncthreads();
      prefix = sh_prefix;
      break;
    }
  }
  // prefix = kth smallest key; keys unique -> exactly 128 keys <= prefix
  const float radius = __uint_as_float((unsigned int)(prefix >> 13));

  if (t == 0){ sh_gcnt = 0u; sh_vote = 0u; }
  __syncthreads();
  for (int j = t; j < NPTS; j += TPB){
    unsigned long long kk = keys[j];
    if (kk <= prefix){
      unsigned int p = atomicAdd(&sh_gcnt, 1u);
      if (p < KNN) skey[p] = kk;
    }
  }
  __syncthreads();

  // bitonic sort 128 keys -> exact top_k order (D asc, idx asc)
  for (int size = 2; size <= KNN; size <<= 1){
    for (int stride = size >> 1; stride > 0; stride >>= 1){
      __syncthreads();
      if (t < KNN){
        int p2 = t ^ stride;
        if (p2 > t){
          unsigned long long av = skey[t], bv = skey[p2];
          bool up = ((t & size) == 0);
          bool sw = up ? (av > bv) : (av < bv);
          if (sw){ skey[t] = bv; skey[p2] = av; }
        }
      }
    }
  }
  __syncthreads();

  // neighborhoods + weights, all f32 per np
  if (t < KNN){
    int j = (int)(skey[t] & 8191ULL);
    float a = V[3 * j + 0] - vx;
    float b = V[3 * j + 1] - vy;
    float c = V[3 * j + 2] - vz;
    nbx[t] = a; nby[t] = b; nbz[t] = c;
    float dd2 = (a * a + b * b) + c * c;
    float dk = sqrtf(fmaxf(dd2, 1e-12f));
    wv[t] = radius - dk;
    idx_out[(size_t)g * KNN + t] = (unsigned short)j;
  }
  __syncthreads();

  if (t == 0){
    // einsum 'nk,nki,nkj->nij': sequential k, (w*n_i)*n_j; lower-tri elements
    float c00 = 0.0f, c10 = 0.0f, c20 = 0.0f, c11 = 0.0f, c21 = 0.0f, c22 = 0.0f;
    for (int k = 0; k < KNN; k++){
      float wn = wv[k], x = nbx[k], y = nby[k], zc = nbz[k];
      c00 += (wn * x) * x;
      c10 += (wn * y) * x;   // cov[1][0]
      c20 += (wn * zc) * x;  // cov[2][0]
      c11 += (wn * y) * y;
      c21 += (wn * zc) * y;  // cov[2][1]
      c22 += (wn * zc) * zc;
    }
    // np.sum(w): pairwise 8-accumulator pattern (n=128)
    float r8[8];
    for (int q = 0; q < 8; q++) r8[q] = wv[q];
    for (int k = 8; k < KNN; k += 8)
      for (int q = 0; q < 8; q++) r8[q] += wv[k + q];
    float wsum = ((r8[0] + r8[1]) + (r8[2] + r8[3])) + ((r8[4] + r8[5]) + (r8[6] + r8[7]));
    float A6[6];
    A6[0] = c00 / wsum; A6[1] = c10 / wsum; A6[2] = c20 / wsum;
    A6[3] = c11 / wsum; A6[4] = c21 / wsum; A6[5] = c22 / wsum;
    float zv[3];
    eigh3_smallest_f32(A6, zv);
    sh_z[0] = zv[0]; sh_z[1] = zv[1]; sh_z[2] = zv[2];
  }
  __syncthreads();
  if (t < KNN){
    float zp = ((nbx[t] * sh_z[0]) + (nby[t] * sh_z[1])) + (nbz[t] * sh_z[2]);
    if (zp >= 0.0f) atomicAdd(&sh_vote, 1u);
  }
  __syncthreads();
  if (t == 0){
    float sg = (sh_vote >= (unsigned)(KNN - sh_vote)) ? 1.0f : -1.0f;
    normals[(size_t)g * 3 + 0] = sg * sh_z[0];
    normals[(size_t)g * 3 + 1] = sg * sh_z[1];
    normals[(size_t)g * 3 + 2] = sg * sh_z[2];
  }
}

// ===================== phase 2: np.mean (sequential k) + normalize =====================
__global__ __launch_bounds__(KNN) void phase2_kernel(const float* __restrict__ normals,
                                                     const unsigned short* __restrict__ idx_in,
                                                     float* __restrict__ out)
{
#pragma clang fp contract(off)
  __shared__ float s0[KNN], s1[KNN], s2[KNN];
  const int g = blockIdx.x;
  const int smp = g >> 13;
  const int t = threadIdx.x;
  const int j = (int)idx_in[(size_t)g * KNN + t];
  const float* nb = normals + (size_t)((smp << 13) + j) * 3;
  s0[t] = nb[0]; s1[t] = nb[1]; s2[t] = nb[2];
  __syncthreads();
  if (t == 0){
    float a0 = 0.0f, a1 = 0.0f, a2 = 0.0f;
    for (int k = 0; k < KNN; k++){ a0 += s0[k]; a1 += s1[k]; a2 += s2[k]; }
    a0 /= 128.0f; a1 /= 128.0f; a2 /= 128.0f;
    float nrm = sqrtf(((a0 * a0) + (a1 * a1)) + (a2 * a2));
    out[(size_t)g * 3 + 0] = a0 / nrm;
    out[(size_t)g * 3 + 1] = a1 / nrm;
    out[(size_t)g * 3 + 2] = a2 / nrm;
  }
}

extern "C" void kernel_launch(void* const* d_in, const int* in_sizes, int n_in,
                              void* d_out, int out_size, void* d_ws, size_t ws_size,
                              hipStream_t stream){
  const float* verts = (const float*)d_in[0];
  float* out = (float*)d_out;
  const int total = in_sizes[0] / 3;   // 2 * 8192 points
  float* normals = (float*)d_ws;
  unsigned short* idxb = (unsigned short*)((char*)d_ws + (size_t)total * 3 * sizeof(float));
  phase1_kernel<<<dim3(total), dim3(TPB), 0, stream>>>(verts, normals, idxb);
  phase2_kernel<<<dim3(total), dim3(KNN), 0, stream>>>(normals, idxb, out);
}

// Round 4
// 821.149 us; speedup vs baseline: 2.5827x; 2.5827x over previous
//
#include <hip/hip_runtime.h>

#define NPTS 8192
#define KNN  128
#define TPB  256

// ============ LAPACK-faithful 3x3 ssyevd (lower), FLOAT32, BLAS-ref op order ============
// UNCHANGED from the passing round (bit-exact path).

__device__ __forceinline__ float f_signf(float a, float b){ return copysignf(a, b); }

__device__ float lapy2f(float x, float y){
#pragma clang fp contract(off)
  float xa = fabsf(x), ya = fabsf(y);
  float w = fmaxf(xa, ya), zz = fminf(xa, ya);
  if (zz == 0.0f) return w;
  float t = zz / w;
  return w * sqrtf(1.0f + t * t);
}

__device__ void slartg_(float f, float g, float &c, float &s, float &r){
#pragma clang fp contract(off)
  const float safmin = 1.17549435e-38f;
  const float safmax = 8.5070592e37f;
  if (g == 0.0f){ c = 1.0f; s = 0.0f; r = f; }
  else if (f == 0.0f){ c = 0.0f; s = f_signf(1.0f, g); r = fabsf(g); }
  else {
    float f1 = fabsf(f), g1 = fabsf(g);
    float rtmin = sqrtf(safmin);
    float rtmax = sqrtf(safmax * 0.5f);
    if (f1 > rtmin && f1 < rtmax && g1 > rtmin && g1 < rtmax){
      float d = sqrtf(f * f + g * g);
      float p = 1.0f / d;
      c = f1 * p;
      s = g * f_signf(p, f);
      r = f_signf(d, f);
    } else {
      float u = fminf(safmax, fmaxf(safmin, fmaxf(f1, g1)));
      float uu = 1.0f / u;
      float fs = f * uu, gs = g * uu;
      float d = sqrtf(fs * fs + gs * gs);
      float p = 1.0f / d;
      c = fabsf(fs) * p;
      s = gs * f_signf(p, f);
      r = f_signf(d, f) * u;
    }
  }
}

__device__ void slaev2_(float a, float b, float cc, float &rt1, float &rt2,
                        float &cs1, float &sn1){
#pragma clang fp contract(off)
  float sm = a + cc;
  float df = a - cc;
  float adf = fabsf(df);
  float tb = b + b;
  float ab = fabsf(tb);
  float acmx, acmn;
  if (fabsf(a) > fabsf(cc)){ acmx = a; acmn = cc; } else { acmx = cc; acmn = a; }
  float rt;
  if (adf > ab){ float t = ab / adf; rt = adf * sqrtf(1.0f + t * t); }
  else if (adf < ab){ float t = adf / ab; rt = ab * sqrtf(1.0f + t * t); }
  else { rt = ab * sqrtf(2.0f); }
  int sgn1;
  if (sm < 0.0f){ rt1 = 0.5f * (sm - rt); sgn1 = -1; rt2 = (acmx / rt1) * acmn - (b / rt1) * b; }
  else if (sm > 0.0f){ rt1 = 0.5f * (sm + rt); sgn1 = 1; rt2 = (acmx / rt1) * acmn - (b / rt1) * b; }
  else { rt1 = 0.5f * rt; rt2 = -0.5f * rt; sgn1 = 1; }
  float cs; int sgn2;
  if (df >= 0.0f){ cs = df + rt; sgn2 = 1; }
  else { cs = df - rt; sgn2 = -1; }
  float acs = fabsf(cs);
  if (acs > ab){
    float ct = -tb / cs;
    sn1 = 1.0f / sqrtf(1.0f + ct * ct);
    cs1 = ct * sn1;
  } else {
    if (ab == 0.0f){ cs1 = 1.0f; sn1 = 0.0f; }
    else {
      float tn = -cs / tb;
      cs1 = 1.0f / sqrtf(1.0f + tn * tn);
      sn1 = tn * cs1;
    }
  }
  if (sgn1 == sgn2){ float tn = cs1; cs1 = -sn1; sn1 = tn; }
}

__device__ void ssteqr3(float *d, float *e, float z[3][3]){
#pragma clang fp contract(off)
  const float eps  = 5.9604645e-8f;
  const float eps2 = 3.5527137e-15f;
  const float safmin = 1.17549435e-38f;
  const int n = 3;
  for (int i = 0; i < 3; i++)
    for (int j = 0; j < 3; j++) z[i][j] = (i == j) ? 1.0f : 0.0f;
  const int nmaxit = n * 30;
  int jtot = 0;
  int l1 = 1;
  int l = 0, lsv = 0, lend = 0, lendsv = 0, m = 0;
  float p, g, r, c, s, f, b;
  float csave[2], ssave[2];
  int safety = 0;

L10:
  if (++safety > 64) goto L190;
  if (l1 > n) goto L160;
  if (l1 > 1) e[l1 - 2] = 0.0f;
  if (l1 <= n - 1){
    for (m = l1; m <= n - 1; m++){
      float tst = fabsf(e[m - 1]);
      if (tst == 0.0f) goto L30;
      if (tst <= (sqrtf(fabsf(d[m - 1])) * sqrtf(fabsf(d[m]))) * eps){ e[m - 1] = 0.0f; goto L30; }
    }
  }
  m = n;
L30:
  l = l1; lsv = l; lend = m; lendsv = lend; l1 = m + 1;
  if (lend == l) goto L10;
  {
    float anorm = fabsf(d[l - 1]);
    for (int q = l; q <= lend - 1; q++){
      anorm = fmaxf(anorm, fabsf(d[q]));
      anorm = fmaxf(anorm, fabsf(e[q - 1]));
    }
    if (anorm == 0.0f) goto L10;
  }
  if (fabsf(d[lend - 1]) < fabsf(d[l - 1])){ lend = lsv; l = lendsv; }
  if (lend > l){
    // QL
L40:
    if (l != lend){
      for (m = l; m <= lend - 1; m++){
        float tst = e[m - 1] * e[m - 1];
        if (tst <= (eps2 * fabsf(d[m - 1])) * fabsf(d[m]) + safmin) goto L60;
      }
    }
    m = lend;
L60:
    if (m < lend) e[m - 1] = 0.0f;
    p = d[l - 1];
    if (m == l) goto L80;
    if (m == l + 1){
      float rt1, rt2;
      slaev2_(d[l - 1], e[l - 1], d[l], rt1, rt2, c, s);
      for (int i2 = 0; i2 < 3; i2++){
        float temp = z[i2][l];
        z[i2][l]     = c * temp - s * z[i2][l - 1];
        z[i2][l - 1] = s * temp + c * z[i2][l - 1];
      }
      d[l - 1] = rt1; d[l] = rt2; e[l - 1] = 0.0f;
      l += 2;
      if (l <= lend) goto L40;
      goto L140;
    }
    if (jtot == nmaxit) goto L140;
    jtot++;
    g = (d[l] - p) / (2.0f * e[l - 1]);
    r = lapy2f(g, 1.0f);
    g = d[m - 1] - p + e[l - 1] / (g + f_signf(r, g));
    s = 1.0f; c = 1.0f; p = 0.0f;
    for (int i2 = m - 1; i2 >= l; i2--){
      f = s * e[i2 - 1];
      b = c * e[i2 - 1];
      slartg_(g, f, c, s, r);
      if (i2 != m - 1) e[i2] = r;
      g = d[i2] - p;
      r = (d[i2 - 1] - g) * s + 2.0f * c * b;
      p = s * r;
      d[i2] = g + p;
      g = c * r - b;
      csave[i2 - l] = c; ssave[i2 - l] = -s;
    }
    {
      int mmc = m - l + 1;
      for (int j2 = mmc - 1; j2 >= 1; j2--){
        float cj = csave[j2 - 1], sj = ssave[j2 - 1];
        if (cj != 1.0f || sj != 0.0f){
          for (int i2 = 0; i2 < 3; i2++){
            float temp = z[i2][(l - 1) + j2];
            z[i2][(l - 1) + j2]     = cj * temp - sj * z[i2][(l - 1) + j2 - 1];
            z[i2][(l - 1) + j2 - 1] = sj * temp + cj * z[i2][(l - 1) + j2 - 1];
          }
        }
      }
    }
    d[l - 1] -= p;
    e[l - 1] = g;
    goto L40;
L80:
    d[l - 1] = p;
    l++;
    if (l <= lend) goto L40;
    goto L140;
  } else {
    // QR
L90:
    if (l != lend){
      for (m = l; m >= lend + 1; m--){
        float tst = e[m - 2] * e[m - 2];
        if (tst <= (eps2 * fabsf(d[m - 1])) * fabsf(d[m - 2]) + safmin) goto L110;
      }
    }
    m = lend;
L110:
    if (m > lend) e[m - 2] = 0.0f;
    p = d[l - 1];
    if (m == l) goto L130;
    if (m == l - 1){
      float rt1, rt2;
      slaev2_(d[l - 2], e[l - 2], d[l - 1], rt1, rt2, c, s);
      for (int i2 = 0; i2 < 3; i2++){
        float temp = z[i2][l - 1];
        z[i2][l - 1] = c * temp - s * z[i2][l - 2];
        z[i2][l - 2] = s * temp + c * z[i2][l - 2];
      }
      d[l - 2] = rt1; d[l - 1] = rt2; e[l - 2] = 0.0f;
      l -= 2;
      if (l >= lend) goto L90;
      goto L140;
    }
    if (jtot == nmaxit) goto L140;
    jtot++;
    g = (d[l - 2] - p) / (2.0f * e[l - 2]);
    r = lapy2f(g, 1.0f);
    g = d[m - 1] - p + e[l - 2] / (g + f_signf(r, g));
    s = 1.0f; c = 1.0f; p = 0.0f;
    for (int i2 = m; i2 <= l - 1; i2++){
      f = s * e[i2 - 1];
      b = c * e[i2 - 1];
      slartg_(g, f, c, s, r);
      if (i2 != m) e[i2 - 2] = r;
      g = d[i2 - 1] - p;
      r = (d[i2] - g) * s + 2.0f * c * b;
      p = s * r;
      d[i2 - 1] = g + p;
      g = c * r - b;
      csave[i2 - m] = c; ssave[i2 - m] = s;
    }
    {
      int cnt = l - m + 1;
      for (int j2 = 1; j2 <= cnt - 1; j2++){
        float cj = csave[j2 - 1], sj = ssave[j2 - 1];
        if (cj != 1.0f || sj != 0.0f){
          for (int i2 = 0; i2 < 3; i2++){
            float temp = z[i2][(m - 1) + j2];
            z[i2][(m - 1) + j2]     = cj * temp - sj * z[i2][(m - 1) + j2 - 1];
            z[i2][(m - 1) + j2 - 1] = sj * temp + cj * z[i2][(m - 1) + j2 - 1];
          }
        }
      }
    }
    d[l - 1] -= p;
    e[l - 2] = g;
    goto L90;
L130:
    d[l - 1] = p;
    l--;
    if (l >= lend) goto L90;
    goto L140;
  }
L140:
  if (jtot < nmaxit) goto L10;
  goto L190;
L160:
  for (int ii = 2; ii <= n; ii++){
    int i2 = ii - 1, k2 = i2;
    float pp = d[i2 - 1];
    for (int j2 = ii; j2 <= n; j2++){
      if (d[j2 - 1] < pp){ k2 = j2; pp = d[j2 - 1]; }
    }
    if (k2 != i2){
      d[k2 - 1] = d[i2 - 1]; d[i2 - 1] = pp;
      for (int r2 = 0; r2 < 3; r2++){
        float tt = z[r2][i2 - 1]; z[r2][i2 - 1] = z[r2][k2 - 1]; z[r2][k2 - 1] = tt;
      }
    }
  }
L190: ;
}

__device__ void eigh3_smallest_f32(const float A6[6], float zout[3]){
#pragma clang fp contract(off)
  float a00 = A6[0], a10 = A6[1], a20 = A6[2], a11 = A6[3], a21 = A6[4], a22 = A6[5];
  float d[3], e[2], tau1 = 0.0f, v2 = 0.0f;
  float xnorm = fabsf(a20);
  if (xnorm == 0.0f){
    tau1 = 0.0f;
    d[0] = a00; d[1] = a11; d[2] = a22; e[0] = a10; e[1] = a21;
  } else {
    float alpha = a10;
    float beta = -f_signf(lapy2f(alpha, xnorm), alpha);
    tau1 = (beta - alpha) / beta;
    float rsc = 1.0f / (alpha - beta);
    v2 = a20 * rsc;
    float y1 = tau1 * a11 + tau1 * (a21 * v2);
    float y2 = tau1 * a21 + (tau1 * v2) * a22;
    float dotv = y1 + y2 * v2;
    float al = (-0.5f * tau1) * dotv;
    float w1 = y1 + al;
    float w2 = y2 + al * v2;
    d[0] = a00;
    d[1] = (a11 + (-w1)) + (w1 * (-1.0f));
    e[1] = (a21 + v2 * (-w1)) + (w2 * (-1.0f));
    d[2] = (a22 + v2 * (-w2)) + (w2 * (-v2));
    e[0] = beta;
  }
  float z[3][3];
  ssteqr3(d, e, z);
  if (tau1 != 0.0f){
    for (int j = 0; j < 3; j++){
      float wj = z[1][j] + z[2][j] * v2;
      float tmp = (-tau1) * wj;
      z[1][j] = z[1][j] + tmp;
      z[2][j] = z[2][j] + v2 * tmp;
    }
  }
  zout[0] = z[0][0]; zout[1] = z[1][0]; zout[2] = z[2][0];
}

// ===================== phase 1 =====================
__global__ __launch_bounds__(TPB) void phase1_kernel(const float* __restrict__ verts,
                                                     float* __restrict__ normals,
                                                     unsigned short* __restrict__ idx_out)
{
#pragma clang fp contract(off)
  __shared__ unsigned int dbits[NPTS];        // 32 KiB: f32 D bit patterns
  __shared__ unsigned long long skey[KNN];    // (Dbits<<13)|idx sort keys for the 128
  __shared__ float nbx[KNN], nby[KNN], nbz[KNN], wv[KNN];
  __shared__ unsigned int bins[256];
  __shared__ unsigned int eqbuf[128];
  __shared__ unsigned int wsum4[4];
  __shared__ unsigned int sh_prefix;
  __shared__ unsigned int sh_kt, sh_cnt, sh_lt, sh_eq, sh_vote;
  __shared__ float sh_z[3];

  const int g   = blockIdx.x;
  const int smp = g >> 13;
  const int i   = g & (NPTS - 1);
  const int t   = threadIdx.x;
  const float* V = verts + (size_t)smp * NPTS * 3;

  const float vx = V[3 * i + 0], vy = V[3 * i + 1], vz = V[3 * i + 2];
  const float sqi = (vx * vx + vy * vy) + vz * vz;

  // f32 D per np formula (identical to passing round)
#pragma unroll 4
  for (int j = t; j < NPTS; j += TPB){
    float a = V[3 * j + 0], b = V[3 * j + 1], c = V[3 * j + 2];
    float dot = fmaf(vz, c, fmaf(vy, b, vx * a));
    float sqj = (a * a + b * b) + c * c;
    float d2 = (sqi - 2.0f * dot) + sqj;
    float D = sqrtf(fmaxf(d2, 1e-12f));
    dbits[j] = __float_as_uint(D);
  }
  __syncthreads();

  // ---- radix-select the 128th smallest u32 key; PARALLEL bin scan ----
  unsigned int prefix = 0u;
  unsigned int kt = KNN;
  unsigned int cnt = 0u;
  for (int level = 0; level < 4; level++){
    const int shift = 24 - 8 * level;
    bins[t] = 0u;
    __syncthreads();
#pragma unroll 4
    for (int j = t; j < NPTS; j += TPB){
      unsigned int bits = dbits[j];
      if (level == 0 || (bits >> (shift + 8)) == (prefix >> (shift + 8)))
        atomicAdd(&bins[(bits >> shift) & 255u], 1u);
    }
    __syncthreads();
    // parallel inclusive prefix over 256 bins (4 waves)
    {
      unsigned int c = bins[t];
      unsigned int incl = c;
      #pragma unroll
      for (int off = 1; off < 64; off <<= 1){
        unsigned int nv = (unsigned int)__shfl_up((int)incl, off, 64);
        if ((t & 63) >= off) incl += nv;
      }
      if ((t & 63) == 63) wsum4[t >> 6] = incl;
      __syncthreads();
      unsigned int base = 0u;
      #pragma unroll
      for (int w = 0; w < 3; w++) if (w < (t >> 6)) base += wsum4[w];
      incl += base;
      unsigned int excl = incl - c;
      if (c > 0u && excl < kt && kt <= incl){
        sh_prefix = prefix | ((unsigned int)t << shift);
        sh_kt = kt - excl;
        sh_cnt = c;
      }
    }
    __syncthreads();
    prefix = sh_prefix; kt = sh_kt; cnt = sh_cnt;
    __syncthreads();
    if (cnt == 1u && level < 3){
      // unique element in selected bin: fetch its full bits in parallel
      for (int j = t; j < NPTS; j += TPB){
        unsigned int bits = dbits[j];
        if ((bits >> shift) == (prefix >> shift)) sh_prefix = bits;
      }
      __syncthreads();
      prefix = sh_prefix;
      break;
    }
  }
  const unsigned int T = prefix;          // 128th smallest D bits
  const unsigned int need_rank = kt;      // how many to take from the ==T group
  const float radius = __uint_as_float(T);

  // gather: all strictly below T, plus smallest-index ties at T
  if (t == 0){ sh_lt = 0u; sh_eq = 0u; sh_vote = 0u; }
  __syncthreads();
#pragma unroll 4
  for (int j = t; j < NPTS; j += TPB){
    unsigned int bits = dbits[j];
    if (bits < T){
      unsigned int p = atomicAdd(&sh_lt, 1u);
      if (p < KNN) skey[p] = (((unsigned long long)bits) << 13) | (unsigned long long)j;
    } else if (bits == T){
      unsigned int p = atomicAdd(&sh_eq, 1u);
      if (p < 128u) eqbuf[p] = (unsigned int)j;
    }
  }
  __syncthreads();
  if (t == 0){
    unsigned int clt = sh_lt; if (clt > KNN) clt = KNN;
    unsigned int ceq = sh_eq; if (ceq > 128u) ceq = 128u;
    for (unsigned int a2 = 1; a2 < ceq; a2++){
      unsigned int vv = eqbuf[a2]; int b2 = (int)a2 - 1;
      while (b2 >= 0 && eqbuf[b2] > vv){ eqbuf[b2 + 1] = eqbuf[b2]; b2--; }
      eqbuf[b2 + 1] = vv;
    }
    unsigned int need = KNN - clt;
    if (need > ceq) need = ceq;
    (void)need_rank;
    for (unsigned int q = 0; q < need; q++)
      skey[clt + q] = (((unsigned long long)T) << 13) | (unsigned long long)eqbuf[q];
  }
  __syncthreads();

  // bitonic sort 128 u64 keys -> exact top_k order (D asc, idx asc)
  for (int size = 2; size <= KNN; size <<= 1){
    for (int stride = size >> 1; stride > 0; stride >>= 1){
      __syncthreads();
      if (t < KNN){
        int p2 = t ^ stride;
        if (p2 > t){
          unsigned long long av = skey[t], bv = skey[p2];
          bool up = ((t & size) == 0);
          bool sw = up ? (av > bv) : (av < bv);
          if (sw){ skey[t] = bv; skey[p2] = av; }
        }
      }
    }
  }
  __syncthreads();

  // neighborhoods + weights (identical numerics)
  if (t < KNN){
    int j = (int)(skey[t] & 8191ULL);
    float a = V[3 * j + 0] - vx;
    float b = V[3 * j + 1] - vy;
    float c = V[3 * j + 2] - vz;
    nbx[t] = a; nby[t] = b; nbz[t] = c;
    float dd2 = (a * a + b * b) + c * c;
    float dk = sqrtf(fmaxf(dd2, 1e-12f));
    wv[t] = radius - dk;
    idx_out[(size_t)g * KNN + t] = (unsigned short)j;
  }
  __syncthreads();

  if (t == 0){
    // einsum 'nk,nki,nkj->nij': sequential k, (w*n_i)*n_j; lower-tri elements
    float c00 = 0.0f, c10 = 0.0f, c20 = 0.0f, c11 = 0.0f, c21 = 0.0f, c22 = 0.0f;
    for (int k = 0; k < KNN; k++){
      float wn = wv[k], x = nbx[k], y = nby[k], zc = nbz[k];
      c00 += (wn * x) * x;
      c10 += (wn * y) * x;
      c20 += (wn * zc) * x;
      c11 += (wn * y) * y;
      c21 += (wn * zc) * y;
      c22 += (wn * zc) * zc;
    }
    // np.sum(w): pairwise 8-accumulator pattern (n=128)
    float r8[8];
    for (int q = 0; q < 8; q++) r8[q] = wv[q];
    for (int k = 8; k < KNN; k += 8)
      for (int q = 0; q < 8; q++) r8[q] += wv[k + q];
    float wsum = ((r8[0] + r8[1]) + (r8[2] + r8[3])) + ((r8[4] + r8[5]) + (r8[6] + r8[7]));
    float A6[6];
    A6[0] = c00 / wsum; A6[1] = c10 / wsum; A6[2] = c20 / wsum;
    A6[3] = c11 / wsum; A6[4] = c21 / wsum; A6[5] = c22 / wsum;
    float zv[3];
    eigh3_smallest_f32(A6, zv);
    sh_z[0] = zv[0]; sh_z[1] = zv[1]; sh_z[2] = zv[2];
  }
  __syncthreads();
  if (t < KNN){
    float zp = ((nbx[t] * sh_z[0]) + (nby[t] * sh_z[1])) + (nbz[t] * sh_z[2]);
    if (zp >= 0.0f) atomicAdd(&sh_vote, 1u);
  }
  __syncthreads();
  if (t == 0){
    float sg = (sh_vote >= (unsigned)(KNN - sh_vote)) ? 1.0f : -1.0f;
    normals[(size_t)g * 3 + 0] = sg * sh_z[0];
    normals[(size_t)g * 3 + 1] = sg * sh_z[1];
    normals[(size_t)g * 3 + 2] = sg * sh_z[2];
  }
}

// ===================== phase 2: np.mean (sequential k) + normalize =====================
__global__ __launch_bounds__(KNN) void phase2_kernel(const float* __restrict__ normals,
                                                     const unsigned short* __restrict__ idx_in,
                                                     float* __restrict__ out)
{
#pragma clang fp contract(off)
  __shared__ float s0[KNN], s1[KNN], s2[KNN];
  const int g = blockIdx.x;
  const int smp = g >> 13;
  const int t = threadIdx.x;
  const int j = (int)idx_in[(size_t)g * KNN + t];
  const float* nb = normals + (size_t)((smp << 13) + j) * 3;
  s0[t] = nb[0]; s1[t] = nb[1]; s2[t] = nb[2];
  __syncthreads();
  if (t == 0){
    float a0 = 0.0f, a1 = 0.0f, a2 = 0.0f;
    for (int k = 0; k < KNN; k++){ a0 += s0[k]; a1 += s1[k]; a2 += s2[k]; }
    a0 /= 128.0f; a1 /= 128.0f; a2 /= 128.0f;
    float nrm = sqrtf(((a0 * a0) + (a1 * a1)) + (a2 * a2));
    out[(size_t)g * 3 + 0] = a0 / nrm;
    out[(size_t)g * 3 + 1] = a1 / nrm;
    out[(size_t)g * 3 + 2] = a2 / nrm;
  }
}

extern "C" void kernel_launch(void* const* d_in, const int* in_sizes, int n_in,
                              void* d_out, int out_size, void* d_ws, size_t ws_size,
                              hipStream_t stream){
  const float* verts = (const float*)d_in[0];
  float* out = (float*)d_out;
  const int total = in_sizes[0] / 3;   // 2 * 8192 points
  float* normals = (float*)d_ws;
  unsigned short* idxb = (unsigned short*)((char*)d_ws + (size_t)total * 3 * sizeof(float));
  phase1_kernel<<<dim3(total), dim3(TPB), 0, stream>>>(verts, normals, idxb);
  phase2_kernel<<<dim3(total), dim3(KNN), 0, stream>>>(normals, idxb, out);
}

// Round 5
// 745.637 us; speedup vs baseline: 2.8442x; 1.1013x over previous
//
#include <hip/hip_runtime.h>

#define NPTS 8192
#define KNN  128
#define TPB  512

// ============ LAPACK-faithful 3x3 ssyevd (lower), FLOAT32, BLAS-ref op order ============
// UNCHANGED from the passing rounds (bit-exact path).

__device__ __forceinline__ float f_signf(float a, float b){ return copysignf(a, b); }

__device__ float lapy2f(float x, float y){
#pragma clang fp contract(off)
  float xa = fabsf(x), ya = fabsf(y);
  float w = fmaxf(xa, ya), zz = fminf(xa, ya);
  if (zz == 0.0f) return w;
  float t = zz / w;
  return w * sqrtf(1.0f + t * t);
}

__device__ void slartg_(float f, float g, float &c, float &s, float &r){
#pragma clang fp contract(off)
  const float safmin = 1.17549435e-38f;
  const float safmax = 8.5070592e37f;
  if (g == 0.0f){ c = 1.0f; s = 0.0f; r = f; }
  else if (f == 0.0f){ c = 0.0f; s = f_signf(1.0f, g); r = fabsf(g); }
  else {
    float f1 = fabsf(f), g1 = fabsf(g);
    float rtmin = sqrtf(safmin);
    float rtmax = sqrtf(safmax * 0.5f);
    if (f1 > rtmin && f1 < rtmax && g1 > rtmin && g1 < rtmax){
      float d = sqrtf(f * f + g * g);
      float p = 1.0f / d;
      c = f1 * p;
      s = g * f_signf(p, f);
      r = f_signf(d, f);
    } else {
      float u = fminf(safmax, fmaxf(safmin, fmaxf(f1, g1)));
      float uu = 1.0f / u;
      float fs = f * uu, gs = g * uu;
      float d = sqrtf(fs * fs + gs * gs);
      float p = 1.0f / d;
      c = fabsf(fs) * p;
      s = gs * f_signf(p, f);
      r = f_signf(d, f) * u;
    }
  }
}

__device__ void slaev2_(float a, float b, float cc, float &rt1, float &rt2,
                        float &cs1, float &sn1){
#pragma clang fp contract(off)
  float sm = a + cc;
  float df = a - cc;
  float adf = fabsf(df);
  float tb = b + b;
  float ab = fabsf(tb);
  float acmx, acmn;
  if (fabsf(a) > fabsf(cc)){ acmx = a; acmn = cc; } else { acmx = cc; acmn = a; }
  float rt;
  if (adf > ab){ float t = ab / adf; rt = adf * sqrtf(1.0f + t * t); }
  else if (adf < ab){ float t = adf / ab; rt = ab * sqrtf(1.0f + t * t); }
  else { rt = ab * sqrtf(2.0f); }
  int sgn1;
  if (sm < 0.0f){ rt1 = 0.5f * (sm - rt); sgn1 = -1; rt2 = (acmx / rt1) * acmn - (b / rt1) * b; }
  else if (sm > 0.0f){ rt1 = 0.5f * (sm + rt); sgn1 = 1; rt2 = (acmx / rt1) * acmn - (b / rt1) * b; }
  else { rt1 = 0.5f * rt; rt2 = -0.5f * rt; sgn1 = 1; }
  float cs; int sgn2;
  if (df >= 0.0f){ cs = df + rt; sgn2 = 1; }
  else { cs = df - rt; sgn2 = -1; }
  float acs = fabsf(cs);
  if (acs > ab){
    float ct = -tb / cs;
    sn1 = 1.0f / sqrtf(1.0f + ct * ct);
    cs1 = ct * sn1;
  } else {
    if (ab == 0.0f){ cs1 = 1.0f; sn1 = 0.0f; }
    else {
      float tn = -cs / tb;
      cs1 = 1.0f / sqrtf(1.0f + tn * tn);
      sn1 = tn * cs1;
    }
  }
  if (sgn1 == sgn2){ float tn = cs1; cs1 = -sn1; sn1 = tn; }
}

__device__ void ssteqr3(float *d, float *e, float z[3][3]){
#pragma clang fp contract(off)
  const float eps  = 5.9604645e-8f;
  const float eps2 = 3.5527137e-15f;
  const float safmin = 1.17549435e-38f;
  const int n = 3;
  for (int i = 0; i < 3; i++)
    for (int j = 0; j < 3; j++) z[i][j] = (i == j) ? 1.0f : 0.0f;
  const int nmaxit = n * 30;
  int jtot = 0;
  int l1 = 1;
  int l = 0, lsv = 0, lend = 0, lendsv = 0, m = 0;
  float p, g, r, c, s, f, b;
  float csave[2], ssave[2];
  int safety = 0;

L10:
  if (++safety > 64) goto L190;
  if (l1 > n) goto L160;
  if (l1 > 1) e[l1 - 2] = 0.0f;
  if (l1 <= n - 1){
    for (m = l1; m <= n - 1; m++){
      float tst = fabsf(e[m - 1]);
      if (tst == 0.0f) goto L30;
      if (tst <= (sqrtf(fabsf(d[m - 1])) * sqrtf(fabsf(d[m]))) * eps){ e[m - 1] = 0.0f; goto L30; }
    }
  }
  m = n;
L30:
  l = l1; lsv = l; lend = m; lendsv = lend; l1 = m + 1;
  if (lend == l) goto L10;
  {
    float anorm = fabsf(d[l - 1]);
    for (int q = l; q <= lend - 1; q++){
      anorm = fmaxf(anorm, fabsf(d[q]));
      anorm = fmaxf(anorm, fabsf(e[q - 1]));
    }
    if (anorm == 0.0f) goto L10;
  }
  if (fabsf(d[lend - 1]) < fabsf(d[l - 1])){ lend = lsv; l = lendsv; }
  if (lend > l){
    // QL
L40:
    if (l != lend){
      for (m = l; m <= lend - 1; m++){
        float tst = e[m - 1] * e[m - 1];
        if (tst <= (eps2 * fabsf(d[m - 1])) * fabsf(d[m]) + safmin) goto L60;
      }
    }
    m = lend;
L60:
    if (m < lend) e[m - 1] = 0.0f;
    p = d[l - 1];
    if (m == l) goto L80;
    if (m == l + 1){
      float rt1, rt2;
      slaev2_(d[l - 1], e[l - 1], d[l], rt1, rt2, c, s);
      for (int i2 = 0; i2 < 3; i2++){
        float temp = z[i2][l];
        z[i2][l]     = c * temp - s * z[i2][l - 1];
        z[i2][l - 1] = s * temp + c * z[i2][l - 1];
      }
      d[l - 1] = rt1; d[l] = rt2; e[l - 1] = 0.0f;
      l += 2;
      if (l <= lend) goto L40;
      goto L140;
    }
    if (jtot == nmaxit) goto L140;
    jtot++;
    g = (d[l] - p) / (2.0f * e[l - 1]);
    r = lapy2f(g, 1.0f);
    g = d[m - 1] - p + e[l - 1] / (g + f_signf(r, g));
    s = 1.0f; c = 1.0f; p = 0.0f;
    for (int i2 = m - 1; i2 >= l; i2--){
      f = s * e[i2 - 1];
      b = c * e[i2 - 1];
      slartg_(g, f, c, s, r);
      if (i2 != m - 1) e[i2] = r;
      g = d[i2] - p;
      r = (d[i2 - 1] - g) * s + 2.0f * c * b;
      p = s * r;
      d[i2] = g + p;
      g = c * r - b;
      csave[i2 - l] = c; ssave[i2 - l] = -s;
    }
    {
      int mmc = m - l + 1;
      for (int j2 = mmc - 1; j2 >= 1; j2--){
        float cj = csave[j2 - 1], sj = ssave[j2 - 1];
        if (cj != 1.0f || sj != 0.0f){
          for (int i2 = 0; i2 < 3; i2++){
            float temp = z[i2][(l - 1) + j2];
            z[i2][(l - 1) + j2]     = cj * temp - sj * z[i2][(l - 1) + j2 - 1];
            z[i2][(l - 1) + j2 - 1] = sj * temp + cj * z[i2][(l - 1) + j2 - 1];
          }
        }
      }
    }
    d[l - 1] -= p;
    e[l - 1] = g;
    goto L40;
L80:
    d[l - 1] = p;
    l++;
    if (l <= lend) goto L40;
    goto L140;
  } else {
    // QR
L90:
    if (l != lend){
      for (m = l; m >= lend + 1; m--){
        float tst = e[m - 2] * e[m - 2];
        if (tst <= (eps2 * fabsf(d[m - 1])) * fabsf(d[m - 2]) + safmin) goto L110;
      }
    }
    m = lend;
L110:
    if (m > lend) e[m - 2] = 0.0f;
    p = d[l - 1];
    if (m == l) goto L130;
    if (m == l - 1){
      float rt1, rt2;
      slaev2_(d[l - 2], e[l - 2], d[l - 1], rt1, rt2, c, s);
      for (int i2 = 0; i2 < 3; i2++){
        float temp = z[i2][l - 1];
        z[i2][l - 1] = c * temp - s * z[i2][l - 2];
        z[i2][l - 2] = s * temp + c * z[i2][l - 2];
      }
      d[l - 2] = rt1; d[l - 1] = rt2; e[l - 2] = 0.0f;
      l -= 2;
      if (l >= lend) goto L90;
      goto L140;
    }
    if (jtot == nmaxit) goto L140;
    jtot++;
    g = (d[l - 2] - p) / (2.0f * e[l - 2]);
    r = lapy2f(g, 1.0f);
    g = d[m - 1] - p + e[l - 2] / (g + f_signf(r, g));
    s = 1.0f; c = 1.0f; p = 0.0f;
    for (int i2 = m; i2 <= l - 1; i2++){
      f = s * e[i2 - 1];
      b = c * e[i2 - 1];
      slartg_(g, f, c, s, r);
      if (i2 != m) e[i2 - 2] = r;
      g = d[i2 - 1] - p;
      r = (d[i2] - g) * s + 2.0f * c * b;
      p = s * r;
      d[i2 - 1] = g + p;
      g = c * r - b;
      csave[i2 - m] = c; ssave[i2 - m] = s;
    }
    {
      int cnt = l - m + 1;
      for (int j2 = 1; j2 <= cnt - 1; j2++){
        float cj = csave[j2 - 1], sj = ssave[j2 - 1];
        if (cj != 1.0f || sj != 0.0f){
          for (int i2 = 0; i2 < 3; i2++){
            float temp = z[i2][(m - 1) + j2];
            z[i2][(m - 1) + j2]     = cj * temp - sj * z[i2][(m - 1) + j2 - 1];
            z[i2][(m - 1) + j2 - 1] = sj * temp + cj * z[i2][(m - 1) + j2 - 1];
          }
        }
      }
    }
    d[l - 1] -= p;
    e[l - 2] = g;
    goto L90;
L130:
    d[l - 1] = p;
    l--;
    if (l >= lend) goto L90;
    goto L140;
  }
L140:
  if (jtot < nmaxit) goto L10;
  goto L190;
L160:
  for (int ii = 2; ii <= n; ii++){
    int i2 = ii - 1, k2 = i2;
    float pp = d[i2 - 1];
    for (int j2 = ii; j2 <= n; j2++){
      if (d[j2 - 1] < pp){ k2 = j2; pp = d[j2 - 1]; }
    }
    if (k2 != i2){
      d[k2 - 1] = d[i2 - 1]; d[i2 - 1] = pp;
      for (int r2 = 0; r2 < 3; r2++){
        float tt = z[r2][i2 - 1]; z[r2][i2 - 1] = z[r2][k2 - 1]; z[r2][k2 - 1] = tt;
      }
    }
  }
L190: ;
}

__device__ void eigh3_smallest_f32(const float A6[6], float zout[3]){
#pragma clang fp contract(off)
  float a00 = A6[0], a10 = A6[1], a20 = A6[2], a11 = A6[3], a21 = A6[4], a22 = A6[5];
  float d[3], e[2], tau1 = 0.0f, v2 = 0.0f;
  float xnorm = fabsf(a20);
  if (xnorm == 0.0f){
    tau1 = 0.0f;
    d[0] = a00; d[1] = a11; d[2] = a22; e[0] = a10; e[1] = a21;
  } else {
    float alpha = a10;
    float beta = -f_signf(lapy2f(alpha, xnorm), alpha);
    tau1 = (beta - alpha) / beta;
    float rsc = 1.0f / (alpha - beta);
    v2 = a20 * rsc;
    float y1 = tau1 * a11 + tau1 * (a21 * v2);
    float y2 = tau1 * a21 + (tau1 * v2) * a22;
    float dotv = y1 + y2 * v2;
    float al = (-0.5f * tau1) * dotv;
    float w1 = y1 + al;
    float w2 = y2 + al * v2;
    d[0] = a00;
    d[1] = (a11 + (-w1)) + (w1 * (-1.0f));
    e[1] = (a21 + v2 * (-w1)) + (w2 * (-1.0f));
    d[2] = (a22 + v2 * (-w2)) + (w2 * (-v2));
    e[0] = beta;
  }
  float z[3][3];
  ssteqr3(d, e, z);
  if (tau1 != 0.0f){
    for (int j = 0; j < 3; j++){
      float wj = z[1][j] + z[2][j] * v2;
      float tmp = (-tau1) * wj;
      z[1][j] = z[1][j] + tmp;
      z[2][j] = z[2][j] + v2 * tmp;
    }
  }
  zout[0] = z[0][0]; zout[1] = z[1][0]; zout[2] = z[2][0];
}

// ===================== phase 1 =====================
__global__ __launch_bounds__(TPB) void phase1_kernel(const float* __restrict__ verts,
                                                     float* __restrict__ normals,
                                                     unsigned short* __restrict__ idx_out)
{
#pragma clang fp contract(off)
  __shared__ unsigned int dbits[NPTS];        // 32 KiB: f32 D bit patterns
  __shared__ unsigned long long skey[KNN];    // (Dbits<<13)|idx sort keys
  __shared__ float nbx[KNN], nby[KNN], nbz[KNN], wv[KNN];
  __shared__ unsigned int bins[4][256];       // 4 KiB, 4-copy histogram (eqbuf overlays later)
  __shared__ unsigned int wsum4[4];
  __shared__ unsigned int sh_prefix;
  __shared__ unsigned int sh_kt, sh_cnt, sh_lt, sh_eq, sh_vote;
  __shared__ float sh_z[3];
  __shared__ float sh_c[8];                   // 6 cov partials + wsum

  const int g   = blockIdx.x;
  const int smp = g >> 13;
  const int i   = g & (NPTS - 1);
  const int t   = threadIdx.x;
  const float* V = verts + (size_t)smp * NPTS * 3;

  const float vx = V[3 * i + 0], vy = V[3 * i + 1], vz = V[3 * i + 2];
  const float sqi = (vx * vx + vy * vy) + vz * vz;

  // f32 D per np formula (bit-identical to passing rounds)
#pragma unroll 4
  for (int j = t; j < NPTS; j += TPB){
    float a = V[3 * j + 0], b = V[3 * j + 1], c = V[3 * j + 2];
    float dot = fmaf(vz, c, fmaf(vy, b, vx * a));
    float sqj = (a * a + b * b) + c * c;
    float d2 = (sqi - 2.0f * dot) + sqj;
    float D = sqrtf(fmaxf(d2, 1e-12f));
    dbits[j] = __float_as_uint(D);
  }
  __syncthreads();

  // ---- radix-select 128th smallest u32; 4-copy histogram + parallel scan ----
  unsigned int prefix = 0u;
  unsigned int kt = KNN;
  unsigned int cnt = 0u;
  unsigned int* binflat = &bins[0][0];
  for (int level = 0; level < 4; level++){
    const int shift = 24 - 8 * level;
    binflat[t] = 0u; binflat[t + 512] = 0u;
    __syncthreads();
#pragma unroll 4
    for (int j = t; j < NPTS; j += TPB){
      unsigned int bits = dbits[j];
      if (level == 0 || (bits >> (shift + 8)) == (prefix >> (shift + 8)))
        atomicAdd(&bins[(t >> 6) & 3][(bits >> shift) & 255u], 1u);
    }
    __syncthreads();
    unsigned int cbin = 0u, incl = 0u;
    if (t < 256){
      cbin = bins[0][t] + bins[1][t] + bins[2][t] + bins[3][t];
      incl = cbin;
      #pragma unroll
      for (int off = 1; off < 64; off <<= 1){
        unsigned int nv = (unsigned int)__shfl_up((int)incl, off, 64);
        if ((t & 63) >= off) incl += nv;
      }
      if ((t & 63) == 63) wsum4[t >> 6] = incl;
    }
    __syncthreads();
    if (t < 256){
      unsigned int base = 0u;
      #pragma unroll
      for (int w = 0; w < 3; w++) if (w < (t >> 6)) base += wsum4[w];
      incl += base;
      unsigned int excl = incl - cbin;
      if (cbin > 0u && excl < kt && kt <= incl){
        sh_prefix = prefix | ((unsigned int)t << shift);
        sh_kt = kt - excl;
        sh_cnt = cbin;
      }
    }
    __syncthreads();
    prefix = sh_prefix; kt = sh_kt; cnt = sh_cnt;
    __syncthreads();
    if (cnt == 1u && level < 3){
      for (int j = t; j < NPTS; j += TPB){
        unsigned int bits = dbits[j];
        if ((bits >> shift) == (prefix >> shift)) sh_prefix = bits;
      }
      __syncthreads();
      prefix = sh_prefix;
      break;
    }
  }
  const unsigned int T = prefix;          // 128th smallest D bits
  const float radius = __uint_as_float(T);

  // gather: all strictly below T, plus smallest-index ties at T
  unsigned int* eqbuf = &bins[0][0];      // bins dead from here; reuse 512 B
  if (t == 0){ sh_lt = 0u; sh_eq = 0u; sh_vote = 0u; }
  __syncthreads();
#pragma unroll 4
  for (int j = t; j < NPTS; j += TPB){
    unsigned int bits = dbits[j];
    if (bits < T){
      unsigned int p = atomicAdd(&sh_lt, 1u);
      if (p < KNN) skey[p] = (((unsigned long long)bits) << 13) | (unsigned long long)j;
    } else if (bits == T){
      unsigned int p = atomicAdd(&sh_eq, 1u);
      if (p < 128u) eqbuf[p] = (unsigned int)j;
    }
  }
  __syncthreads();
  if (t == 0){
    unsigned int clt = sh_lt; if (clt > KNN) clt = KNN;
    unsigned int ceq = sh_eq; if (ceq > 128u) ceq = 128u;
    for (unsigned int a2 = 1; a2 < ceq; a2++){
      unsigned int vv = eqbuf[a2]; int b2 = (int)a2 - 1;
      while (b2 >= 0 && eqbuf[b2] > vv){ eqbuf[b2 + 1] = eqbuf[b2]; b2--; }
      eqbuf[b2 + 1] = vv;
    }
    unsigned int need = KNN - clt;
    if (need > ceq) need = ceq;
    for (unsigned int q = 0; q < need; q++)
      skey[clt + q] = (((unsigned long long)T) << 13) | (unsigned long long)eqbuf[q];
  }
  __syncthreads();

  // bitonic sort 128 u64 keys -> exact top_k order (D asc, idx asc)
  for (int size = 2; size <= KNN; size <<= 1){
    for (int stride = size >> 1; stride > 0; stride >>= 1){
      __syncthreads();
      if (t < KNN){
        int p2 = t ^ stride;
        if (p2 > t){
          unsigned long long av = skey[t], bv = skey[p2];
          bool up = ((t & size) == 0);
          bool sw = up ? (av > bv) : (av < bv);
          if (sw){ skey[t] = bv; skey[p2] = av; }
        }
      }
    }
  }
  __syncthreads();

  // neighborhoods + weights (identical numerics)
  if (t < KNN){
    int j = (int)(skey[t] & 8191ULL);
    float a = V[3 * j + 0] - vx;
    float b = V[3 * j + 1] - vy;
    float c = V[3 * j + 2] - vz;
    nbx[t] = a; nby[t] = b; nbz[t] = c;
    float dd2 = (a * a + b * b) + c * c;
    float dk = sqrtf(fmaxf(dd2, 1e-12f));
    wv[t] = radius - dk;
    idx_out[(size_t)g * KNN + t] = (unsigned short)j;
  }
  __syncthreads();

  // covariance: 6 lanes, each the IDENTICAL sequential per-component chain
  if (t < 8){
    if (t < 6){
      float acc = 0.0f;
      for (int k = 0; k < KNN; k++){
        float wn = wv[k], x = nbx[k], y = nby[k], zc = nbz[k];
        float u = (t == 0) ? x : ((t == 1 || t == 3) ? y : zc);
        float v = (t < 3) ? x : ((t < 5) ? y : zc);
        acc += (wn * u) * v;    // c00,c10,c20,c11,c21,c22 for t=0..5
      }
      sh_c[t] = acc;
    } else if (t == 6){
      // np.sum(w): pairwise 8-accumulator pattern (n=128)
      float r8[8];
      for (int q = 0; q < 8; q++) r8[q] = wv[q];
      for (int k = 8; k < KNN; k += 8)
        for (int q = 0; q < 8; q++) r8[q] += wv[k + q];
      sh_c[6] = ((r8[0] + r8[1]) + (r8[2] + r8[3])) + ((r8[4] + r8[5]) + (r8[6] + r8[7]));
    }
  }
  __syncthreads();
  if (t == 0){
    float wsum = sh_c[6];
    float A6[6];
    A6[0] = sh_c[0] / wsum; A6[1] = sh_c[1] / wsum; A6[2] = sh_c[2] / wsum;
    A6[3] = sh_c[3] / wsum; A6[4] = sh_c[4] / wsum; A6[5] = sh_c[5] / wsum;
    float zv[3];
    eigh3_smallest_f32(A6, zv);
    sh_z[0] = zv[0]; sh_z[1] = zv[1]; sh_z[2] = zv[2];
  }
  __syncthreads();
  if (t < KNN){
    float zp = ((nbx[t] * sh_z[0]) + (nby[t] * sh_z[1])) + (nbz[t] * sh_z[2]);
    if (zp >= 0.0f) atomicAdd(&sh_vote, 1u);
  }
  __syncthreads();
  if (t == 0){
    float sg = (sh_vote >= (unsigned)(KNN - sh_vote)) ? 1.0f : -1.0f;
    normals[(size_t)g * 3 + 0] = sg * sh_z[0];
    normals[(size_t)g * 3 + 1] = sg * sh_z[1];
    normals[(size_t)g * 3 + 2] = sg * sh_z[2];
  }
}

// ===================== phase 2: np.mean (sequential k) + normalize =====================
__global__ __launch_bounds__(KNN) void phase2_kernel(const float* __restrict__ normals,
                                                     const unsigned short* __restrict__ idx_in,
                                                     float* __restrict__ out)
{
#pragma clang fp contract(off)
  __shared__ float s0[KNN], s1[KNN], s2[KNN];
  const int g = blockIdx.x;
  const int smp = g >> 13;
  const int t = threadIdx.x;
  const int j = (int)idx_in[(size_t)g * KNN + t];
  const float* nb = normals + (size_t)((smp << 13) + j) * 3;
  s0[t] = nb[0]; s1[t] = nb[1]; s2[t] = nb[2];
  __syncthreads();
  if (t == 0){
    float a0 = 0.0f, a1 = 0.0f, a2 = 0.0f;
    for (int k = 0; k < KNN; k++){ a0 += s0[k]; a1 += s1[k]; a2 += s2[k]; }
    a0 /= 128.0f; a1 /= 128.0f; a2 /= 128.0f;
    float nrm = sqrtf(((a0 * a0) + (a1 * a1)) + (a2 * a2));
    out[(size_t)g * 3 + 0] = a0 / nrm;
    out[(size_t)g * 3 + 1] = a1 / nrm;
    out[(size_t)g * 3 + 2] = a2 / nrm;
  }
}

extern "C" void kernel_launch(void* const* d_in, const int* in_sizes, int n_in,
                              void* d_out, int out_size, void* d_ws, size_t ws_size,
                              hipStream_t stream){
  const float* verts = (const float*)d_in[0];
  float* out = (float*)d_out;
  const int total = in_sizes[0] / 3;   // 2 * 8192 points
  float* normals = (float*)d_ws;
  unsigned short* idxb = (unsigned short*)((char*)d_ws + (size_t)total * 3 * sizeof(float));
  phase1_kernel<<<dim3(total), dim3(TPB), 0, stream>>>(verts, normals, idxb);
  phase2_kernel<<<dim3(total), dim3(KNN), 0, stream>>>(normals, idxb, out);
}

// Round 6
// 652.942 us; speedup vs baseline: 3.2480x; 1.1420x over previous
//
#include <hip/hip_runtime.h>

#define NPTS 8192
#define KNN  128
#define TPB  512

// ============ LAPACK-faithful 3x3 ssyevd (lower), FLOAT32, BLAS-ref op order ============
// UNCHANGED from the passing rounds (bit-exact path).

__device__ __forceinline__ float f_signf(float a, float b){ return copysignf(a, b); }

__device__ float lapy2f(float x, float y){
#pragma clang fp contract(off)
  float xa = fabsf(x), ya = fabsf(y);
  float w = fmaxf(xa, ya), zz = fminf(xa, ya);
  if (zz == 0.0f) return w;
  float t = zz / w;
  return w * sqrtf(1.0f + t * t);
}

__device__ void slartg_(float f, float g, float &c, float &s, float &r){
#pragma clang fp contract(off)
  const float safmin = 1.17549435e-38f;
  const float safmax = 8.5070592e37f;
  if (g == 0.0f){ c = 1.0f; s = 0.0f; r = f; }
  else if (f == 0.0f){ c = 0.0f; s = f_signf(1.0f, g); r = fabsf(g); }
  else {
    float f1 = fabsf(f), g1 = fabsf(g);
    float rtmin = sqrtf(safmin);
    float rtmax = sqrtf(safmax * 0.5f);
    if (f1 > rtmin && f1 < rtmax && g1 > rtmin && g1 < rtmax){
      float d = sqrtf(f * f + g * g);
      float p = 1.0f / d;
      c = f1 * p;
      s = g * f_signf(p, f);
      r = f_signf(d, f);
    } else {
      float u = fminf(safmax, fmaxf(safmin, fmaxf(f1, g1)));
      float uu = 1.0f / u;
      float fs = f * uu, gs = g * uu;
      float d = sqrtf(fs * fs + gs * gs);
      float p = 1.0f / d;
      c = fabsf(fs) * p;
      s = gs * f_signf(p, f);
      r = f_signf(d, f) * u;
    }
  }
}

__device__ void slaev2_(float a, float b, float cc, float &rt1, float &rt2,
                        float &cs1, float &sn1){
#pragma clang fp contract(off)
  float sm = a + cc;
  float df = a - cc;
  float adf = fabsf(df);
  float tb = b + b;
  float ab = fabsf(tb);
  float acmx, acmn;
  if (fabsf(a) > fabsf(cc)){ acmx = a; acmn = cc; } else { acmx = cc; acmn = a; }
  float rt;
  if (adf > ab){ float t = ab / adf; rt = adf * sqrtf(1.0f + t * t); }
  else if (adf < ab){ float t = adf / ab; rt = ab * sqrtf(1.0f + t * t); }
  else { rt = ab * sqrtf(2.0f); }
  int sgn1;
  if (sm < 0.0f){ rt1 = 0.5f * (sm - rt); sgn1 = -1; rt2 = (acmx / rt1) * acmn - (b / rt1) * b; }
  else if (sm > 0.0f){ rt1 = 0.5f * (sm + rt); sgn1 = 1; rt2 = (acmx / rt1) * acmn - (b / rt1) * b; }
  else { rt1 = 0.5f * rt; rt2 = -0.5f * rt; sgn1 = 1; }
  float cs; int sgn2;
  if (df >= 0.0f){ cs = df + rt; sgn2 = 1; }
  else { cs = df - rt; sgn2 = -1; }
  float acs = fabsf(cs);
  if (acs > ab){
    float ct = -tb / cs;
    sn1 = 1.0f / sqrtf(1.0f + ct * ct);
    cs1 = ct * sn1;
  } else {
    if (ab == 0.0f){ cs1 = 1.0f; sn1 = 0.0f; }
    else {
      float tn = -cs / tb;
      cs1 = 1.0f / sqrtf(1.0f + tn * tn);
      sn1 = tn * cs1;
    }
  }
  if (sgn1 == sgn2){ float tn = cs1; cs1 = -sn1; sn1 = tn; }
}

__device__ void ssteqr3(float *d, float *e, float z[3][3]){
#pragma clang fp contract(off)
  const float eps  = 5.9604645e-8f;
  const float eps2 = 3.5527137e-15f;
  const float safmin = 1.17549435e-38f;
  const int n = 3;
  for (int i = 0; i < 3; i++)
    for (int j = 0; j < 3; j++) z[i][j] = (i == j) ? 1.0f : 0.0f;
  const int nmaxit = n * 30;
  int jtot = 0;
  int l1 = 1;
  int l = 0, lsv = 0, lend = 0, lendsv = 0, m = 0;
  float p, g, r, c, s, f, b;
  float csave[2], ssave[2];
  int safety = 0;

L10:
  if (++safety > 64) goto L190;
  if (l1 > n) goto L160;
  if (l1 > 1) e[l1 - 2] = 0.0f;
  if (l1 <= n - 1){
    for (m = l1; m <= n - 1; m++){
      float tst = fabsf(e[m - 1]);
      if (tst == 0.0f) goto L30;
      if (tst <= (sqrtf(fabsf(d[m - 1])) * sqrtf(fabsf(d[m]))) * eps){ e[m - 1] = 0.0f; goto L30; }
    }
  }
  m = n;
L30:
  l = l1; lsv = l; lend = m; lendsv = lend; l1 = m + 1;
  if (lend == l) goto L10;
  {
    float anorm = fabsf(d[l - 1]);
    for (int q = l; q <= lend - 1; q++){
      anorm = fmaxf(anorm, fabsf(d[q]));
      anorm = fmaxf(anorm, fabsf(e[q - 1]));
    }
    if (anorm == 0.0f) goto L10;
  }
  if (fabsf(d[lend - 1]) < fabsf(d[l - 1])){ lend = lsv; l = lendsv; }
  if (lend > l){
    // QL
L40:
    if (l != lend){
      for (m = l; m <= lend - 1; m++){
        float tst = e[m - 1] * e[m - 1];
        if (tst <= (eps2 * fabsf(d[m - 1])) * fabsf(d[m]) + safmin) goto L60;
      }
    }
    m = lend;
L60:
    if (m < lend) e[m - 1] = 0.0f;
    p = d[l - 1];
    if (m == l) goto L80;
    if (m == l + 1){
      float rt1, rt2;
      slaev2_(d[l - 1], e[l - 1], d[l], rt1, rt2, c, s);
      for (int i2 = 0; i2 < 3; i2++){
        float temp = z[i2][l];
        z[i2][l]     = c * temp - s * z[i2][l - 1];
        z[i2][l - 1] = s * temp + c * z[i2][l - 1];
      }
      d[l - 1] = rt1; d[l] = rt2; e[l - 1] = 0.0f;
      l += 2;
      if (l <= lend) goto L40;
      goto L140;
    }
    if (jtot == nmaxit) goto L140;
    jtot++;
    g = (d[l] - p) / (2.0f * e[l - 1]);
    r = lapy2f(g, 1.0f);
    g = d[m - 1] - p + e[l - 1] / (g + f_signf(r, g));
    s = 1.0f; c = 1.0f; p = 0.0f;
    for (int i2 = m - 1; i2 >= l; i2--){
      f = s * e[i2 - 1];
      b = c * e[i2 - 1];
      slartg_(g, f, c, s, r);
      if (i2 != m - 1) e[i2] = r;
      g = d[i2] - p;
      r = (d[i2 - 1] - g) * s + 2.0f * c * b;
      p = s * r;
      d[i2] = g + p;
      g = c * r - b;
      csave[i2 - l] = c; ssave[i2 - l] = -s;
    }
    {
      int mmc = m - l + 1;
      for (int j2 = mmc - 1; j2 >= 1; j2--){
        float cj = csave[j2 - 1], sj = ssave[j2 - 1];
        if (cj != 1.0f || sj != 0.0f){
          for (int i2 = 0; i2 < 3; i2++){
            float temp = z[i2][(l - 1) + j2];
            z[i2][(l - 1) + j2]     = cj * temp - sj * z[i2][(l - 1) + j2 - 1];
            z[i2][(l - 1) + j2 - 1] = sj * temp + cj * z[i2][(l - 1) + j2 - 1];
          }
        }
      }
    }
    d[l - 1] -= p;
    e[l - 1] = g;
    goto L40;
L80:
    d[l - 1] = p;
    l++;
    if (l <= lend) goto L40;
    goto L140;
  } else {
    // QR
L90:
    if (l != lend){
      for (m = l; m >= lend + 1; m--){
        float tst = e[m - 2] * e[m - 2];
        if (tst <= (eps2 * fabsf(d[m - 1])) * fabsf(d[m - 2]) + safmin) goto L110;
      }
    }
    m = lend;
L110:
    if (m > lend) e[m - 2] = 0.0f;
    p = d[l - 1];
    if (m == l) goto L130;
    if (m == l - 1){
      float rt1, rt2;
      slaev2_(d[l - 2], e[l - 2], d[l - 1], rt1, rt2, c, s);
      for (int i2 = 0; i2 < 3; i2++){
        float temp = z[i2][l - 1];
        z[i2][l - 1] = c * temp - s * z[i2][l - 2];
        z[i2][l - 2] = s * temp + c * z[i2][l - 2];
      }
      d[l - 2] = rt1; d[l - 1] = rt2; e[l - 2] = 0.0f;
      l -= 2;
      if (l >= lend) goto L90;
      goto L140;
    }
    if (jtot == nmaxit) goto L140;
    jtot++;
    g = (d[l - 2] - p) / (2.0f * e[l - 2]);
    r = lapy2f(g, 1.0f);
    g = d[m - 1] - p + e[l - 2] / (g + f_signf(r, g));
    s = 1.0f; c = 1.0f; p = 0.0f;
    for (int i2 = m; i2 <= l - 1; i2++){
      f = s * e[i2 - 1];
      b = c * e[i2 - 1];
      slartg_(g, f, c, s, r);
      if (i2 != m) e[i2 - 2] = r;
      g = d[i2 - 1] - p;
      r = (d[i2] - g) * s + 2.0f * c * b;
      p = s * r;
      d[i2 - 1] = g + p;
      g = c * r - b;
      csave[i2 - m] = c; ssave[i2 - m] = s;
    }
    {
      int cnt = l - m + 1;
      for (int j2 = 1; j2 <= cnt - 1; j2++){
        float cj = csave[j2 - 1], sj = ssave[j2 - 1];
        if (cj != 1.0f || sj != 0.0f){
          for (int i2 = 0; i2 < 3; i2++){
            float temp = z[i2][(m - 1) + j2];
            z[i2][(m - 1) + j2]     = cj * temp - sj * z[i2][(m - 1) + j2 - 1];
            z[i2][(m - 1) + j2 - 1] = sj * temp + cj * z[i2][(m - 1) + j2 - 1];
          }
        }
      }
    }
    d[l - 1] -= p;
    e[l - 2] = g;
    goto L90;
L130:
    d[l - 1] = p;
    l--;
    if (l >= lend) goto L90;
    goto L140;
  }
L140:
  if (jtot < nmaxit) goto L10;
  goto L190;
L160:
  for (int ii = 2; ii <= n; ii++){
    int i2 = ii - 1, k2 = i2;
    float pp = d[i2 - 1];
    for (int j2 = ii; j2 <= n; j2++){
      if (d[j2 - 1] < pp){ k2 = j2; pp = d[j2 - 1]; }
    }
    if (k2 != i2){
      d[k2 - 1] = d[i2 - 1]; d[i2 - 1] = pp;
      for (int r2 = 0; r2 < 3; r2++){
        float tt = z[r2][i2 - 1]; z[r2][i2 - 1] = z[r2][k2 - 1]; z[r2][k2 - 1] = tt;
      }
    }
  }
L190: ;
}

__device__ void eigh3_smallest_f32(const float A6[6], float zout[3]){
#pragma clang fp contract(off)
  float a00 = A6[0], a10 = A6[1], a20 = A6[2], a11 = A6[3], a21 = A6[4], a22 = A6[5];
  float d[3], e[2], tau1 = 0.0f, v2 = 0.0f;
  float xnorm = fabsf(a20);
  if (xnorm == 0.0f){
    tau1 = 0.0f;
    d[0] = a00; d[1] = a11; d[2] = a22; e[0] = a10; e[1] = a21;
  } else {
    float alpha = a10;
    float beta = -f_signf(lapy2f(alpha, xnorm), alpha);
    tau1 = (beta - alpha) / beta;
    float rsc = 1.0f / (alpha - beta);
    v2 = a20 * rsc;
    float y1 = tau1 * a11 + tau1 * (a21 * v2);
    float y2 = tau1 * a21 + (tau1 * v2) * a22;
    float dotv = y1 + y2 * v2;
    float al = (-0.5f * tau1) * dotv;
    float w1 = y1 + al;
    float w2 = y2 + al * v2;
    d[0] = a00;
    d[1] = (a11 + (-w1)) + (w1 * (-1.0f));
    e[1] = (a21 + v2 * (-w1)) + (w2 * (-1.0f));
    d[2] = (a22 + v2 * (-w2)) + (w2 * (-v2));
    e[0] = beta;
  }
  float z[3][3];
  ssteqr3(d, e, z);
  if (tau1 != 0.0f){
    for (int j = 0; j < 3; j++){
      float wj = z[1][j] + z[2][j] * v2;
      float tmp = (-tau1) * wj;
      z[1][j] = z[1][j] + tmp;
      z[2][j] = z[2][j] + v2 * tmp;
    }
  }
  zout[0] = z[0][0]; zout[1] = z[1][0]; zout[2] = z[2][0];
}

// ===================== phase 1 =====================
__global__ __launch_bounds__(TPB) void phase1_kernel(const float* __restrict__ verts,
                                                     float* __restrict__ normals,
                                                     unsigned short* __restrict__ idx_out)
{
#pragma clang fp contract(off)
  __shared__ unsigned int dbits[NPTS];        // 32 KiB: f32 D bit patterns
  __shared__ unsigned long long cand[512];    // 4 KiB; aliased as bins[4][256] during radix
  __shared__ unsigned long long skey[KNN];    // sorted (Dbits<<13)|idx
  __shared__ float nbx[KNN], nby[KNN], nbz[KNN], wv[KNN];
  __shared__ unsigned int wsum4[4];
  __shared__ unsigned int sh_prefix;
  __shared__ unsigned int sh_kt, sh_cnt, sh_lt, sh_vote;
  __shared__ float sh_z[3];
  __shared__ float sh_c[8];

  const int g   = blockIdx.x;
  const int smp = g >> 13;
  const int i   = g & (NPTS - 1);
  const int t   = threadIdx.x;
  const float* V = verts + (size_t)smp * NPTS * 3;
  unsigned int* bins = (unsigned int*)cand;

  const float vx = V[3 * i + 0], vy = V[3 * i + 1], vz = V[3 * i + 2];
  const float sqi = (vx * vx + vy * vy) + vz * vz;

  // f32 D per np formula (bit-identical to passing rounds)
#pragma unroll 4
  for (int j = t; j < NPTS; j += TPB){
    float a = V[3 * j + 0], b = V[3 * j + 1], c = V[3 * j + 2];
    float dot = fmaf(vz, c, fmaf(vy, b, vx * a));
    float sqj = (a * a + b * b) + c * c;
    float d2 = (sqi - 2.0f * dot) + sqj;
    float D = sqrtf(fmaxf(d2, 1e-12f));
    dbits[j] = __float_as_uint(D);
  }
  __syncthreads();

  // ---- adaptive radix: narrow until the selected bin holds <=256 keys ----
  unsigned int prefix = 0u;
  unsigned int kt = KNN;
  unsigned int cnt = 0u;
  int stop_shift = 0;
  for (int level = 0; level < 4; level++){
    const int shift = 24 - 8 * level;
    bins[t] = 0u; bins[t + 512] = 0u;
    __syncthreads();
#pragma unroll 4
    for (int j = t; j < NPTS; j += TPB){
      unsigned int bits = dbits[j];
      if (level == 0 || (bits >> (shift + 8)) == (prefix >> (shift + 8)))
        atomicAdd(&bins[((t >> 6) & 3) * 256 + ((bits >> shift) & 255u)], 1u);
    }
    __syncthreads();
    unsigned int cbin = 0u, incl = 0u;
    if (t < 256){
      cbin = bins[t] + bins[256 + t] + bins[512 + t] + bins[768 + t];
      incl = cbin;
      #pragma unroll
      for (int off = 1; off < 64; off <<= 1){
        unsigned int nv = (unsigned int)__shfl_up((int)incl, off, 64);
        if ((t & 63) >= off) incl += nv;
      }
      if ((t & 63) == 63) wsum4[t >> 6] = incl;
    }
    __syncthreads();
    if (t < 256){
      unsigned int base = 0u;
      #pragma unroll
      for (int w = 0; w < 3; w++) if (w < (t >> 6)) base += wsum4[w];
      incl += base;
      unsigned int excl = incl - cbin;
      if (cbin > 0u && excl < kt && kt <= incl){
        sh_prefix = prefix | ((unsigned int)t << shift);
        sh_kt = kt - excl;
        sh_cnt = cbin;
      }
    }
    __syncthreads();
    prefix = sh_prefix; kt = sh_kt; cnt = sh_cnt;
    stop_shift = shift;
    __syncthreads();
    if (cnt <= 256u) break;
  }

  // ---- gather candidates: all keys with (bits>>s) <= (prefix>>s) ----
  const unsigned int P = prefix >> stop_shift;
  if (t == 0){ sh_lt = 0u; sh_vote = 0u; }
  __syncthreads();
#pragma unroll 4
  for (int j = t; j < NPTS; j += TPB){
    unsigned int bits = dbits[j];
    if ((bits >> stop_shift) <= P){
      unsigned int p = atomicAdd(&sh_lt, 1u);
      if (p < 512u) cand[p] = (((unsigned long long)bits) << 13) | (unsigned long long)j;
    }
  }
  __syncthreads();
  unsigned int candN = sh_lt; if (candN > 512u) candN = 512u;

  // ---- rank sort: exact np top_k order (D asc, idx asc), no bank conflicts ----
  if (t < (int)candN){
    unsigned long long key = cand[t];
    unsigned int rank = 0;
    for (unsigned int j = 0; j < candN; j++) rank += (cand[j] < key) ? 1u : 0u;
    if (rank < KNN) skey[rank] = key;
  }
  __syncthreads();

  const float radius = __uint_as_float((unsigned int)(skey[KNN - 1] >> 13));

  // neighborhoods + weights (identical numerics)
  if (t < KNN){
    int j = (int)(skey[t] & 8191ULL);
    float a = V[3 * j + 0] - vx;
    float b = V[3 * j + 1] - vy;
    float c = V[3 * j + 2] - vz;
    nbx[t] = a; nby[t] = b; nbz[t] = c;
    float dd2 = (a * a + b * b) + c * c;
    float dk = sqrtf(fmaxf(dd2, 1e-12f));
    wv[t] = radius - dk;
    idx_out[(size_t)g * KNN + t] = (unsigned short)j;
  }
  __syncthreads();

  // covariance: 6 lanes, each the IDENTICAL sequential per-component chain
  if (t < 8){
    if (t < 6){
      float acc = 0.0f;
      for (int k = 0; k < KNN; k++){
        float wn = wv[k], x = nbx[k], y = nby[k], zc = nbz[k];
        float u = (t == 0) ? x : ((t == 1 || t == 3) ? y : zc);
        float v = (t < 3) ? x : ((t < 5) ? y : zc);
        acc += (wn * u) * v;    // c00,c10,c20,c11,c21,c22 for t=0..5
      }
      sh_c[t] = acc;
    } else if (t == 6){
      // np.sum(w): pairwise 8-accumulator pattern (n=128)
      float r8[8];
      for (int q = 0; q < 8; q++) r8[q] = wv[q];
      for (int k = 8; k < KNN; k += 8)
        for (int q = 0; q < 8; q++) r8[q] += wv[k + q];
      sh_c[6] = ((r8[0] + r8[1]) + (r8[2] + r8[3])) + ((r8[4] + r8[5]) + (r8[6] + r8[7]));
    }
  }
  __syncthreads();
  if (t == 0){
    float wsum = sh_c[6];
    float A6[6];
    A6[0] = sh_c[0] / wsum; A6[1] = sh_c[1] / wsum; A6[2] = sh_c[2] / wsum;
    A6[3] = sh_c[3] / wsum; A6[4] = sh_c[4] / wsum; A6[5] = sh_c[5] / wsum;
    float zv[3];
    eigh3_smallest_f32(A6, zv);
    sh_z[0] = zv[0]; sh_z[1] = zv[1]; sh_z[2] = zv[2];
  }
  __syncthreads();
  if (t < KNN){
    float zp = ((nbx[t] * sh_z[0]) + (nby[t] * sh_z[1])) + (nbz[t] * sh_z[2]);
    if (zp >= 0.0f) atomicAdd(&sh_vote, 1u);
  }
  __syncthreads();
  if (t == 0){
    float sg = (sh_vote >= (unsigned)(KNN - sh_vote)) ? 1.0f : -1.0f;
    normals[(size_t)g * 3 + 0] = sg * sh_z[0];
    normals[(size_t)g * 3 + 1] = sg * sh_z[1];
    normals[(size_t)g * 3 + 2] = sg * sh_z[2];
  }
}

// ===================== phase 2: np.mean (sequential k) + normalize =====================
__global__ __launch_bounds__(KNN) void phase2_kernel(const float* __restrict__ normals,
                                                     const unsigned short* __restrict__ idx_in,
                                                     float* __restrict__ out)
{
#pragma clang fp contract(off)
  __shared__ float s0[KNN], s1[KNN], s2[KNN];
  const int g = blockIdx.x;
  const int smp = g >> 13;
  const int t = threadIdx.x;
  const int j = (int)idx_in[(size_t)g * KNN + t];
  const float* nb = normals + (size_t)((smp << 13) + j) * 3;
  s0[t] = nb[0]; s1[t] = nb[1]; s2[t] = nb[2];
  __syncthreads();
  if (t == 0){
    float a0 = 0.0f, a1 = 0.0f, a2 = 0.0f;
    for (int k = 0; k < KNN; k++){ a0 += s0[k]; a1 += s1[k]; a2 += s2[k]; }
    a0 /= 128.0f; a1 /= 128.0f; a2 /= 128.0f;
    float nrm = sqrtf(((a0 * a0) + (a1 * a1)) + (a2 * a2));
    out[(size_t)g * 3 + 0] = a0 / nrm;
    out[(size_t)g * 3 + 1] = a1 / nrm;
    out[(size_t)g * 3 + 2] = a2 / nrm;
  }
}

extern "C" void kernel_launch(void* const* d_in, const int* in_sizes, int n_in,
                              void* d_out, int out_size, void* d_ws, size_t ws_size,
                              hipStream_t stream){
  const float* verts = (const float*)d_in[0];
  float* out = (float*)d_out;
  const int total = in_sizes[0] / 3;   // 2 * 8192 points
  float* normals = (float*)d_ws;
  unsigned short* idxb = (unsigned short*)((char*)d_ws + (size_t)total * 3 * sizeof(float));
  phase1_kernel<<<dim3(total), dim3(TPB), 0, stream>>>(verts, normals, idxb);
  phase2_kernel<<<dim3(total), dim3(KNN), 0, stream>>>(normals, idxb, out);
}

// Round 7
// 486.011 us; speedup vs baseline: 4.3636x; 1.3435x over previous
//
#include <hip/hip_runtime.h>

#define NPTS 8192
#define KNN  128
#define TPB  256
#define WPB  4            // waves per block
#define CANDCAP 384       // max candidates: <=127 below-bin + <=256 in-bin

// ============ LAPACK-faithful 3x3 ssyevd (lower), FLOAT32, BLAS-ref op order ============
// UNCHANGED from the passing rounds (bit-exact path).

__device__ __forceinline__ float f_signf(float a, float b){ return copysignf(a, b); }

__device__ float lapy2f(float x, float y){
#pragma clang fp contract(off)
  float xa = fabsf(x), ya = fabsf(y);
  float w = fmaxf(xa, ya), zz = fminf(xa, ya);
  if (zz == 0.0f) return w;
  float t = zz / w;
  return w * sqrtf(1.0f + t * t);
}

__device__ void slartg_(float f, float g, float &c, float &s, float &r){
#pragma clang fp contract(off)
  const float safmin = 1.17549435e-38f;
  const float safmax = 8.5070592e37f;
  if (g == 0.0f){ c = 1.0f; s = 0.0f; r = f; }
  else if (f == 0.0f){ c = 0.0f; s = f_signf(1.0f, g); r = fabsf(g); }
  else {
    float f1 = fabsf(f), g1 = fabsf(g);
    float rtmin = sqrtf(safmin);
    float rtmax = sqrtf(safmax * 0.5f);
    if (f1 > rtmin && f1 < rtmax && g1 > rtmin && g1 < rtmax){
      float d = sqrtf(f * f + g * g);
      float p = 1.0f / d;
      c = f1 * p;
      s = g * f_signf(p, f);
      r = f_signf(d, f);
    } else {
      float u = fminf(safmax, fmaxf(safmin, fmaxf(f1, g1)));
      float uu = 1.0f / u;
      float fs = f * uu, gs = g * uu;
      float d = sqrtf(fs * fs + gs * gs);
      float p = 1.0f / d;
      c = fabsf(fs) * p;
      s = gs * f_signf(p, f);
      r = f_signf(d, f) * u;
    }
  }
}

__device__ void slaev2_(float a, float b, float cc, float &rt1, float &rt2,
                        float &cs1, float &sn1){
#pragma clang fp contract(off)
  float sm = a + cc;
  float df = a - cc;
  float adf = fabsf(df);
  float tb = b + b;
  float ab = fabsf(tb);
  float acmx, acmn;
  if (fabsf(a) > fabsf(cc)){ acmx = a; acmn = cc; } else { acmx = cc; acmn = a; }
  float rt;
  if (adf > ab){ float t = ab / adf; rt = adf * sqrtf(1.0f + t * t); }
  else if (adf < ab){ float t = adf / ab; rt = ab * sqrtf(1.0f + t * t); }
  else { rt = ab * sqrtf(2.0f); }
  int sgn1;
  if (sm < 0.0f){ rt1 = 0.5f * (sm - rt); sgn1 = -1; rt2 = (acmx / rt1) * acmn - (b / rt1) * b; }
  else if (sm > 0.0f){ rt1 = 0.5f * (sm + rt); sgn1 = 1; rt2 = (acmx / rt1) * acmn - (b / rt1) * b; }
  else { rt1 = 0.5f * rt; rt2 = -0.5f * rt; sgn1 = 1; }
  float cs; int sgn2;
  if (df >= 0.0f){ cs = df + rt; sgn2 = 1; }
  else { cs = df - rt; sgn2 = -1; }
  float acs = fabsf(cs);
  if (acs > ab){
    float ct = -tb / cs;
    sn1 = 1.0f / sqrtf(1.0f + ct * ct);
    cs1 = ct * sn1;
  } else {
    if (ab == 0.0f){ cs1 = 1.0f; sn1 = 0.0f; }
    else {
      float tn = -cs / tb;
      cs1 = 1.0f / sqrtf(1.0f + tn * tn);
      sn1 = tn * cs1;
    }
  }
  if (sgn1 == sgn2){ float tn = cs1; cs1 = -sn1; sn1 = tn; }
}

__device__ void ssteqr3(float *d, float *e, float z[3][3]){
#pragma clang fp contract(off)
  const float eps  = 5.9604645e-8f;
  const float eps2 = 3.5527137e-15f;
  const float safmin = 1.17549435e-38f;
  const int n = 3;
  for (int i = 0; i < 3; i++)
    for (int j = 0; j < 3; j++) z[i][j] = (i == j) ? 1.0f : 0.0f;
  const int nmaxit = n * 30;
  int jtot = 0;
  int l1 = 1;
  int l = 0, lsv = 0, lend = 0, lendsv = 0, m = 0;
  float p, g, r, c, s, f, b;
  float csave[2], ssave[2];
  int safety = 0;

L10:
  if (++safety > 64) goto L190;
  if (l1 > n) goto L160;
  if (l1 > 1) e[l1 - 2] = 0.0f;
  if (l1 <= n - 1){
    for (m = l1; m <= n - 1; m++){
      float tst = fabsf(e[m - 1]);
      if (tst == 0.0f) goto L30;
      if (tst <= (sqrtf(fabsf(d[m - 1])) * sqrtf(fabsf(d[m]))) * eps){ e[m - 1] = 0.0f; goto L30; }
    }
  }
  m = n;
L30:
  l = l1; lsv = l; lend = m; lendsv = lend; l1 = m + 1;
  if (lend == l) goto L10;
  {
    float anorm = fabsf(d[l - 1]);
    for (int q = l; q <= lend - 1; q++){
      anorm = fmaxf(anorm, fabsf(d[q]));
      anorm = fmaxf(anorm, fabsf(e[q - 1]));
    }
    if (anorm == 0.0f) goto L10;
  }
  if (fabsf(d[lend - 1]) < fabsf(d[l - 1])){ lend = lsv; l = lendsv; }
  if (lend > l){
    // QL
L40:
    if (l != lend){
      for (m = l; m <= lend - 1; m++){
        float tst = e[m - 1] * e[m - 1];
        if (tst <= (eps2 * fabsf(d[m - 1])) * fabsf(d[m]) + safmin) goto L60;
      }
    }
    m = lend;
L60:
    if (m < lend) e[m - 1] = 0.0f;
    p = d[l - 1];
    if (m == l) goto L80;
    if (m == l + 1){
      float rt1, rt2;
      slaev2_(d[l - 1], e[l - 1], d[l], rt1, rt2, c, s);
      for (int i2 = 0; i2 < 3; i2++){
        float temp = z[i2][l];
        z[i2][l]     = c * temp - s * z[i2][l - 1];
        z[i2][l - 1] = s * temp + c * z[i2][l - 1];
      }
      d[l - 1] = rt1; d[l] = rt2; e[l - 1] = 0.0f;
      l += 2;
      if (l <= lend) goto L40;
      goto L140;
    }
    if (jtot == nmaxit) goto L140;
    jtot++;
    g = (d[l] - p) / (2.0f * e[l - 1]);
    r = lapy2f(g, 1.0f);
    g = d[m - 1] - p + e[l - 1] / (g + f_signf(r, g));
    s = 1.0f; c = 1.0f; p = 0.0f;
    for (int i2 = m - 1; i2 >= l; i2--){
      f = s * e[i2 - 1];
      b = c * e[i2 - 1];
      slartg_(g, f, c, s, r);
      if (i2 != m - 1) e[i2] = r;
      g = d[i2] - p;
      r = (d[i2 - 1] - g) * s + 2.0f * c * b;
      p = s * r;
      d[i2] = g + p;
      g = c * r - b;
      csave[i2 - l] = c; ssave[i2 - l] = -s;
    }
    {
      int mmc = m - l + 1;
      for (int j2 = mmc - 1; j2 >= 1; j2--){
        float cj = csave[j2 - 1], sj = ssave[j2 - 1];
        if (cj != 1.0f || sj != 0.0f){
          for (int i2 = 0; i2 < 3; i2++){
            float temp = z[i2][(l - 1) + j2];
            z[i2][(l - 1) + j2]     = cj * temp - sj * z[i2][(l - 1) + j2 - 1];
            z[i2][(l - 1) + j2 - 1] = sj * temp + cj * z[i2][(l - 1) + j2 - 1];
          }
        }
      }
    }
    d[l - 1] -= p;
    e[l - 1] = g;
    goto L40;
L80:
    d[l - 1] = p;
    l++;
    if (l <= lend) goto L40;
    goto L140;
  } else {
    // QR
L90:
    if (l != lend){
      for (m = l; m >= lend + 1; m--){
        float tst = e[m - 2] * e[m - 2];
        if (tst <= (eps2 * fabsf(d[m - 1])) * fabsf(d[m - 2]) + safmin) goto L110;
      }
    }
    m = lend;
L110:
    if (m > lend) e[m - 2] = 0.0f;
    p = d[l - 1];
    if (m == l) goto L130;
    if (m == l - 1){
      float rt1, rt2;
      slaev2_(d[l - 2], e[l - 2], d[l - 1], rt1, rt2, c, s);
      for (int i2 = 0; i2 < 3; i2++){
        float temp = z[i2][l - 1];
        z[i2][l - 1] = c * temp - s * z[i2][l - 2];
        z[i2][l - 2] = s * temp + c * z[i2][l - 2];
      }
      d[l - 2] = rt1; d[l - 1] = rt2; e[l - 2] = 0.0f;
      l -= 2;
      if (l >= lend) goto L90;
      goto L140;
    }
    if (jtot == nmaxit) goto L140;
    jtot++;
    g = (d[l - 2] - p) / (2.0f * e[l - 2]);
    r = lapy2f(g, 1.0f);
    g = d[m - 1] - p + e[l - 2] / (g + f_signf(r, g));
    s = 1.0f; c = 1.0f; p = 0.0f;
    for (int i2 = m; i2 <= l - 1; i2++){
      f = s * e[i2 - 1];
      b = c * e[i2 - 1];
      slartg_(g, f, c, s, r);
      if (i2 != m) e[i2 - 2] = r;
      g = d[i2 - 1] - p;
      r = (d[i2] - g) * s + 2.0f * c * b;
      p = s * r;
      d[i2 - 1] = g + p;
      g = c * r - b;
      csave[i2 - m] = c; ssave[i2 - m] = s;
    }
    {
      int cnt = l - m + 1;
      for (int j2 = 1; j2 <= cnt - 1; j2++){
        float cj = csave[j2 - 1], sj = ssave[j2 - 1];
        if (cj != 1.0f || sj != 0.0f){
          for (int i2 = 0; i2 < 3; i2++){
            float temp = z[i2][(m - 1) + j2];
            z[i2][(m - 1) + j2]     = cj * temp - sj * z[i2][(m - 1) + j2 - 1];
            z[i2][(m - 1) + j2 - 1] = sj * temp + cj * z[i2][(m - 1) + j2 - 1];
          }
        }
      }
    }
    d[l - 1] -= p;
    e[l - 2] = g;
    goto L90;
L130:
    d[l - 1] = p;
    l--;
    if (l >= lend) goto L90;
    goto L140;
  }
L140:
  if (jtot < nmaxit) goto L10;
  goto L190;
L160:
  for (int ii = 2; ii <= n; ii++){
    int i2 = ii - 1, k2 = i2;
    float pp = d[i2 - 1];
    for (int j2 = ii; j2 <= n; j2++){
      if (d[j2 - 1] < pp){ k2 = j2; pp = d[j2 - 1]; }
    }
    if (k2 != i2){
      d[k2 - 1] = d[i2 - 1]; d[i2 - 1] = pp;
      for (int r2 = 0; r2 < 3; r2++){
        float tt = z[r2][i2 - 1]; z[r2][i2 - 1] = z[r2][k2 - 1]; z[r2][k2 - 1] = tt;
      }
    }
  }
L190: ;
}

__device__ void eigh3_smallest_f32(const float A6[6], float zout[3]){
#pragma clang fp contract(off)
  float a00 = A6[0], a10 = A6[1], a20 = A6[2], a11 = A6[3], a21 = A6[4], a22 = A6[5];
  float d[3], e[2], tau1 = 0.0f, v2 = 0.0f;
  float xnorm = fabsf(a20);
  if (xnorm == 0.0f){
    tau1 = 0.0f;
    d[0] = a00; d[1] = a11; d[2] = a22; e[0] = a10; e[1] = a21;
  } else {
    float alpha = a10;
    float beta = -f_signf(lapy2f(alpha, xnorm), alpha);
    tau1 = (beta - alpha) / beta;
    float rsc = 1.0f / (alpha - beta);
    v2 = a20 * rsc;
    float y1 = tau1 * a11 + tau1 * (a21 * v2);
    float y2 = tau1 * a21 + (tau1 * v2) * a22;
    float dotv = y1 + y2 * v2;
    float al = (-0.5f * tau1) * dotv;
    float w1 = y1 + al;
    float w2 = y2 + al * v2;
    d[0] = a00;
    d[1] = (a11 + (-w1)) + (w1 * (-1.0f));
    e[1] = (a21 + v2 * (-w1)) + (w2 * (-1.0f));
    d[2] = (a22 + v2 * (-w2)) + (w2 * (-v2));
    e[0] = beta;
  }
  float z[3][3];
  ssteqr3(d, e, z);
  if (tau1 != 0.0f){
    for (int j = 0; j < 3; j++){
      float wj = z[1][j] + z[2][j] * v2;
      float tmp = (-tau1) * wj;
      z[1][j] = z[1][j] + tmp;
      z[2][j] = z[2][j] + v2 * tmp;
    }
  }
  zout[0] = z[0][0]; zout[1] = z[1][0]; zout[2] = z[2][0];
}

// ===================== wave helpers =====================
__device__ __forceinline__ void wsync(){
  // lockstep wave64 + drain LDS ops; memory clobber = compiler fence
  asm volatile("s_waitcnt lgkmcnt(0)" ::: "memory");
}
__device__ __forceinline__ unsigned int wscan_incl(unsigned int v, int lane){
  #pragma unroll
  for (int off = 1; off < 64; off <<= 1){
    unsigned int n = (unsigned int)__shfl_up((int)v, off, 64);
    if (lane >= off) v += n;
  }
  return v;
}
__device__ __forceinline__ unsigned int lanepos(unsigned long long bal){
  return __builtin_amdgcn_mbcnt_hi((unsigned int)(bal >> 32),
         __builtin_amdgcn_mbcnt_lo((unsigned int)bal, 0u));
}

// D bits per np formula (bit-identical to passing rounds)
#define COMPUTE_BITS(J, BITS) { \
  float a_ = V[3*(J)], b_ = V[3*(J)+1], c_ = V[3*(J)+2]; \
  float dot_ = fmaf(vz, c_, fmaf(vy, b_, vx * a_)); \
  float sqj_ = (a_ * a_ + b_ * b_) + c_ * c_; \
  float d2_ = (sqi - 2.0f * dot_) + sqj_; \
  float D_ = sqrtf(fmaxf(d2_, 1e-12f)); \
  BITS = __float_as_uint(D_); }

// ===================== phase 1: wave-per-query =====================
__global__ __launch_bounds__(TPB, 8) void phase1_kernel(const float* __restrict__ verts,
                                                        float* __restrict__ normals,
                                                        unsigned short* __restrict__ idx_out)
{
#pragma clang fp contract(off)
  __shared__ unsigned long long candAll[WPB * CANDCAP];   // 12 KiB (hist overlays head)
  __shared__ float nbAll[WPB][4 * KNN];                   // 8 KiB (skey overlays head)

  const int t    = threadIdx.x;
  const int w    = t >> 6;
  const int lane = t & 63;
  const int gq   = blockIdx.x * WPB + w;
  const int smp  = gq >> 13;
  const int i    = gq & (NPTS - 1);
  const float* V = verts + (size_t)smp * NPTS * 3;

  unsigned long long* cand = candAll + w * CANDCAP;
  unsigned int* hist = (unsigned int*)cand;               // 256 u32 in first 1 KiB
  float* nbx = &nbAll[w][0];
  float* nby = &nbAll[w][KNN];
  float* nbz = &nbAll[w][2 * KNN];
  float* wvv = &nbAll[w][3 * KNN];
  unsigned long long* skey = (unsigned long long*)&nbAll[w][0];  // 128 u64 = first 1 KiB

  const float vx = V[3 * i + 0], vy = V[3 * i + 1], vz = V[3 * i + 2];
  const float sqi = (vx * vx + vy * vy) + vz * vz;

  // ---- adaptive radix select (per-wave, same semantics as passing rounds) ----
  unsigned int prefix = 0u, kt = KNN, cnt = 0u;
  int stop_shift = 0;
  for (int level = 0; level < 4; level++){
    const int shift = 24 - 8 * level;
    hist[lane] = 0u; hist[lane + 64] = 0u; hist[lane + 128] = 0u; hist[lane + 192] = 0u;
    wsync();
#pragma unroll 4
    for (int k = 0; k < NPTS / 64; k++){
      int j = k * 64 + lane;
      unsigned int bits; COMPUTE_BITS(j, bits);
      if (level == 0 || (bits >> (shift + 8)) == (prefix >> (shift + 8)))
        atomicAdd(&hist[(bits >> shift) & 255u], 1u);
    }
    wsync();
    unsigned int h0 = hist[lane], h1 = hist[lane + 64], h2 = hist[lane + 128], h3 = hist[lane + 192];
    unsigned int s0 = wscan_incl(h0, lane);
    unsigned int s1 = wscan_incl(h1, lane);
    unsigned int s2 = wscan_incl(h2, lane);
    unsigned int s3 = wscan_incl(h3, lane);
    unsigned int tot0 = (unsigned int)__shfl((int)s0, 63, 64);
    unsigned int tot1 = (unsigned int)__shfl((int)s1, 63, 64);
    unsigned int tot2 = (unsigned int)__shfl((int)s2, 63, 64);
    unsigned int i0 = s0;
    unsigned int i1 = s1 + tot0;
    unsigned int i2 = s2 + tot0 + tot1;
    unsigned int i3 = s3 + tot0 + tot1 + tot2;
    unsigned int selb = 0xffffffffu, nkt = 0u, ncnt = 0u;
    if (h0 > 0u && (i0 - h0) < kt && kt <= i0){ selb = (unsigned)lane;        nkt = kt - (i0 - h0); ncnt = h0; }
    if (h1 > 0u && (i1 - h1) < kt && kt <= i1){ selb = (unsigned)lane + 64u;  nkt = kt - (i1 - h1); ncnt = h1; }
    if (h2 > 0u && (i2 - h2) < kt && kt <= i2){ selb = (unsigned)lane + 128u; nkt = kt - (i2 - h2); ncnt = h2; }
    if (h3 > 0u && (i3 - h3) < kt && kt <= i3){ selb = (unsigned)lane + 192u; nkt = kt - (i3 - h3); ncnt = h3; }
    unsigned long long bal = __ballot(selb != 0xffffffffu);
    int src = (int)(__ffsll((long long)bal) - 1);
    selb = (unsigned int)__shfl((int)selb, src, 64);
    nkt  = (unsigned int)__shfl((int)nkt,  src, 64);
    ncnt = (unsigned int)__shfl((int)ncnt, src, 64);
    prefix = prefix | (selb << shift);
    kt = nkt; cnt = ncnt; stop_shift = shift;
    if (cnt <= 256u) break;
  }

  // ---- gather candidates in index order (ballot/mbcnt compaction) ----
  const unsigned int P = prefix >> stop_shift;
  unsigned int base = 0u;
#pragma unroll 2
  for (int k = 0; k < NPTS / 64; k++){
    int j = k * 64 + lane;
    unsigned int bits; COMPUTE_BITS(j, bits);
    bool pred = ((bits >> stop_shift) <= P);
    unsigned long long bal = __ballot(pred);
    unsigned int pos = lanepos(bal);
    if (pred){
      unsigned int p = base + pos;
      if (p < CANDCAP) cand[p] = (((unsigned long long)bits) << 13) | (unsigned long long)j;
    }
    base += (unsigned int)__popcll(bal);
  }
  wsync();
  unsigned int candN = base; if (candN > CANDCAP) candN = CANDCAP;

  // ---- rank sort -> exact np top_k order (D asc, idx asc) ----
  for (unsigned int c = lane; c < candN; c += 64){
    unsigned long long key = cand[c];
    unsigned int rank = 0u;
    for (unsigned int jj = 0; jj < candN; jj++) rank += (cand[jj] < key) ? 1u : 0u;
    if (rank < KNN) skey[rank] = key;
  }
  wsync();

  // ---- read keys, then overwrite region with neighborhoods ----
  const float radius = __uint_as_float((unsigned int)(skey[KNN - 1] >> 13));
  unsigned long long k0 = skey[lane];
  unsigned long long k1 = skey[lane + 64];
  wsync();   // all skey reads complete before nb writes (same region)
  {
    int j0 = (int)(k0 & 8191ULL);
    float a = V[3 * j0 + 0] - vx;
    float b = V[3 * j0 + 1] - vy;
    float c = V[3 * j0 + 2] - vz;
    nbx[lane] = a; nby[lane] = b; nbz[lane] = c;
    float dd2 = (a * a + b * b) + c * c;
    wvv[lane] = radius - sqrtf(fmaxf(dd2, 1e-12f));
    idx_out[(size_t)gq * KNN + lane] = (unsigned short)j0;
  }
  {
    int j1 = (int)(k1 & 8191ULL);
    float a = V[3 * j1 + 0] - vx;
    float b = V[3 * j1 + 1] - vy;
    float c = V[3 * j1 + 2] - vz;
    nbx[lane + 64] = a; nby[lane + 64] = b; nbz[lane + 64] = c;
    float dd2 = (a * a + b * b) + c * c;
    wvv[lane + 64] = radius - sqrtf(fmaxf(dd2, 1e-12f));
    idx_out[(size_t)gq * KNN + 64 + lane] = (unsigned short)j1;
  }
  wsync();

  // ---- covariance: 6 lanes run the IDENTICAL sequential chains; lane 6 = wsum ----
  float acc = 0.0f;
  if (lane < 6){
    for (int k = 0; k < KNN; k++){
      float wn = wvv[k], x = nbx[k], y = nby[k], zc = nbz[k];
      float u = (lane == 0) ? x : ((lane == 1 || lane == 3) ? y : zc);
      float v = (lane < 3) ? x : ((lane < 5) ? y : zc);
      acc += (wn * u) * v;    // c00,c10,c20,c11,c21,c22 for lane=0..5
    }
  } else if (lane == 6){
    float r8[8];
    for (int q = 0; q < 8; q++) r8[q] = wvv[q];
    for (int k = 8; k < KNN; k += 8)
      for (int q = 0; q < 8; q++) r8[q] += wvv[k + q];
    acc = ((r8[0] + r8[1]) + (r8[2] + r8[3])) + ((r8[4] + r8[5]) + (r8[6] + r8[7]));
  }
  float c00 = __shfl(acc, 0, 64), c10 = __shfl(acc, 1, 64), c20 = __shfl(acc, 2, 64);
  float c11 = __shfl(acc, 3, 64), c21 = __shfl(acc, 4, 64), c22 = __shfl(acc, 5, 64);
  float wsum = __shfl(acc, 6, 64);

  // ---- eigh on all lanes redundantly (uniform -> no divergence, no broadcast) ----
  float A6[6];
  A6[0] = c00 / wsum; A6[1] = c10 / wsum; A6[2] = c20 / wsum;
  A6[3] = c11 / wsum; A6[4] = c21 / wsum; A6[5] = c22 / wsum;
  float zv[3];
  eigh3_smallest_f32(A6, zv);

  // ---- vote (exact formula/order), sign, write ----
  float zp0 = ((nbx[lane] * zv[0]) + (nby[lane] * zv[1])) + (nbz[lane] * zv[2]);
  float zp1 = ((nbx[lane + 64] * zv[0]) + (nby[lane + 64] * zv[1])) + (nbz[lane + 64] * zv[2]);
  unsigned int votes = (unsigned int)__popcll(__ballot(zp0 >= 0.0f))
                     + (unsigned int)__popcll(__ballot(zp1 >= 0.0f));
  float sg = (votes >= (unsigned)(KNN - votes)) ? 1.0f : -1.0f;
  if (lane == 0){
    normals[(size_t)gq * 3 + 0] = sg * zv[0];
    normals[(size_t)gq * 3 + 1] = sg * zv[1];
    normals[(size_t)gq * 3 + 2] = sg * zv[2];
  }
}

// ===================== phase 2: wave-per-point average + normalize =====================
__global__ __launch_bounds__(TPB) void phase2_kernel(const float* __restrict__ normals,
                                                     const unsigned short* __restrict__ idx_in,
                                                     float* __restrict__ out)
{
#pragma clang fp contract(off)
  const int t    = threadIdx.x;
  const int w    = t >> 6;
  const int lane = t & 63;
  const int g    = blockIdx.x * WPB + w;
  const int smp  = g >> 13;
  const int base = smp << 13;
  const int j0 = (int)idx_in[(size_t)g * KNN + lane];
  const int j1 = (int)idx_in[(size_t)g * KNN + 64 + lane];
  const float* n0 = normals + (size_t)(base + j0) * 3;
  const float* n1 = normals + (size_t)(base + j1) * 3;
  float a0 = n0[0] + n1[0];
  float a1 = n0[1] + n1[1];
  float a2 = n0[2] + n1[2];
  #pragma unroll
  for (int off = 32; off > 0; off >>= 1){
    a0 += __shfl_down(a0, off, 64);
    a1 += __shfl_down(a1, off, 64);
    a2 += __shfl_down(a2, off, 64);
  }
  if (lane == 0){
    a0 /= 128.0f; a1 /= 128.0f; a2 /= 128.0f;
    float nrm = sqrtf(((a0 * a0) + (a1 * a1)) + (a2 * a2));
    out[(size_t)g * 3 + 0] = a0 / nrm;
    out[(size_t)g * 3 + 1] = a1 / nrm;
    out[(size_t)g * 3 + 2] = a2 / nrm;
  }
}

extern "C" void kernel_launch(void* const* d_in, const int* in_sizes, int n_in,
                              void* d_out, int out_size, void* d_ws, size_t ws_size,
                              hipStream_t stream){
  const float* verts = (const float*)d_in[0];
  float* out = (float*)d_out;
  const int total = in_sizes[0] / 3;   // 2 * 8192 points
  float* normals = (float*)d_ws;
  unsigned short* idxb = (unsigned short*)((char*)d_ws + (size_t)total * 3 * sizeof(float));
  phase1_kernel<<<dim3(total / WPB), dim3(TPB), 0, stream>>>(verts, normals, idxb);
  phase2_kernel<<<dim3(total / WPB), dim3(TPB), 0, stream>>>(normals, idxb, out);
}

// Round 8
// 373.090 us; speedup vs baseline: 5.6843x; 1.3027x over previous
//
#include <hip/hip_runtime.h>

#define NPTS 8192
#define KNN  128
#define TPB  256
#define WPB  4            // waves per block
#define CANDCAP 384       // max candidates: <=127 below-bin + <=256 in-bin

// ============ LAPACK-faithful 3x3 ssyevd (lower), FLOAT32, BLAS-ref op order ============
// UNCHANGED from the passing rounds (bit-exact path).

__device__ __forceinline__ float f_signf(float a, float b){ return copysignf(a, b); }

__device__ float lapy2f(float x, float y){
#pragma clang fp contract(off)
  float xa = fabsf(x), ya = fabsf(y);
  float w = fmaxf(xa, ya), zz = fminf(xa, ya);
  if (zz == 0.0f) return w;
  float t = zz / w;
  return w * sqrtf(1.0f + t * t);
}

__device__ void slartg_(float f, float g, float &c, float &s, float &r){
#pragma clang fp contract(off)
  const float safmin = 1.17549435e-38f;
  const float safmax = 8.5070592e37f;
  if (g == 0.0f){ c = 1.0f; s = 0.0f; r = f; }
  else if (f == 0.0f){ c = 0.0f; s = f_signf(1.0f, g); r = fabsf(g); }
  else {
    float f1 = fabsf(f), g1 = fabsf(g);
    float rtmin = sqrtf(safmin);
    float rtmax = sqrtf(safmax * 0.5f);
    if (f1 > rtmin && f1 < rtmax && g1 > rtmin && g1 < rtmax){
      float d = sqrtf(f * f + g * g);
      float p = 1.0f / d;
      c = f1 * p;
      s = g * f_signf(p, f);
      r = f_signf(d, f);
    } else {
      float u = fminf(safmax, fmaxf(safmin, fmaxf(f1, g1)));
      float uu = 1.0f / u;
      float fs = f * uu, gs = g * uu;
      float d = sqrtf(fs * fs + gs * gs);
      float p = 1.0f / d;
      c = fabsf(fs) * p;
      s = gs * f_signf(p, f);
      r = f_signf(d, f) * u;
    }
  }
}

__device__ void slaev2_(float a, float b, float cc, float &rt1, float &rt2,
                        float &cs1, float &sn1){
#pragma clang fp contract(off)
  float sm = a + cc;
  float df = a - cc;
  float adf = fabsf(df);
  float tb = b + b;
  float ab = fabsf(tb);
  float acmx, acmn;
  if (fabsf(a) > fabsf(cc)){ acmx = a; acmn = cc; } else { acmx = cc; acmn = a; }
  float rt;
  if (adf > ab){ float t = ab / adf; rt = adf * sqrtf(1.0f + t * t); }
  else if (adf < ab){ float t = adf / ab; rt = ab * sqrtf(1.0f + t * t); }
  else { rt = ab * sqrtf(2.0f); }
  int sgn1;
  if (sm < 0.0f){ rt1 = 0.5f * (sm - rt); sgn1 = -1; rt2 = (acmx / rt1) * acmn - (b / rt1) * b; }
  else if (sm > 0.0f){ rt1 = 0.5f * (sm + rt); sgn1 = 1; rt2 = (acmx / rt1) * acmn - (b / rt1) * b; }
  else { rt1 = 0.5f * rt; rt2 = -0.5f * rt; sgn1 = 1; }
  float cs; int sgn2;
  if (df >= 0.0f){ cs = df + rt; sgn2 = 1; }
  else { cs = df - rt; sgn2 = -1; }
  float acs = fabsf(cs);
  if (acs > ab){
    float ct = -tb / cs;
    sn1 = 1.0f / sqrtf(1.0f + ct * ct);
    cs1 = ct * sn1;
  } else {
    if (ab == 0.0f){ cs1 = 1.0f; sn1 = 0.0f; }
    else {
      float tn = -cs / tb;
      cs1 = 1.0f / sqrtf(1.0f + tn * tn);
      sn1 = tn * cs1;
    }
  }
  if (sgn1 == sgn2){ float tn = cs1; cs1 = -sn1; sn1 = tn; }
}

__device__ void ssteqr3(float *d, float *e, float z[3][3]){
#pragma clang fp contract(off)
  const float eps  = 5.9604645e-8f;
  const float eps2 = 3.5527137e-15f;
  const float safmin = 1.17549435e-38f;
  const int n = 3;
  for (int i = 0; i < 3; i++)
    for (int j = 0; j < 3; j++) z[i][j] = (i == j) ? 1.0f : 0.0f;
  const int nmaxit = n * 30;
  int jtot = 0;
  int l1 = 1;
  int l = 0, lsv = 0, lend = 0, lendsv = 0, m = 0;
  float p, g, r, c, s, f, b;
  float csave[2], ssave[2];
  int safety = 0;

L10:
  if (++safety > 64) goto L190;
  if (l1 > n) goto L160;
  if (l1 > 1) e[l1 - 2] = 0.0f;
  if (l1 <= n - 1){
    for (m = l1; m <= n - 1; m++){
      float tst = fabsf(e[m - 1]);
      if (tst == 0.0f) goto L30;
      if (tst <= (sqrtf(fabsf(d[m - 1])) * sqrtf(fabsf(d[m]))) * eps){ e[m - 1] = 0.0f; goto L30; }
    }
  }
  m = n;
L30:
  l = l1; lsv = l; lend = m; lendsv = lend; l1 = m + 1;
  if (lend == l) goto L10;
  {
    float anorm = fabsf(d[l - 1]);
    for (int q = l; q <= lend - 1; q++){
      anorm = fmaxf(anorm, fabsf(d[q]));
      anorm = fmaxf(anorm, fabsf(e[q - 1]));
    }
    if (anorm == 0.0f) goto L10;
  }
  if (fabsf(d[lend - 1]) < fabsf(d[l - 1])){ lend = lsv; l = lendsv; }
  if (lend > l){
    // QL
L40:
    if (l != lend){
      for (m = l; m <= lend - 1; m++){
        float tst = e[m - 1] * e[m - 1];
        if (tst <= (eps2 * fabsf(d[m - 1])) * fabsf(d[m]) + safmin) goto L60;
      }
    }
    m = lend;
L60:
    if (m < lend) e[m - 1] = 0.0f;
    p = d[l - 1];
    if (m == l) goto L80;
    if (m == l + 1){
      float rt1, rt2;
      slaev2_(d[l - 1], e[l - 1], d[l], rt1, rt2, c, s);
      for (int i2 = 0; i2 < 3; i2++){
        float temp = z[i2][l];
        z[i2][l]     = c * temp - s * z[i2][l - 1];
        z[i2][l - 1] = s * temp + c * z[i2][l - 1];
      }
      d[l - 1] = rt1; d[l] = rt2; e[l - 1] = 0.0f;
      l += 2;
      if (l <= lend) goto L40;
      goto L140;
    }
    if (jtot == nmaxit) goto L140;
    jtot++;
    g = (d[l] - p) / (2.0f * e[l - 1]);
    r = lapy2f(g, 1.0f);
    g = d[m - 1] - p + e[l - 1] / (g + f_signf(r, g));
    s = 1.0f; c = 1.0f; p = 0.0f;
    for (int i2 = m - 1; i2 >= l; i2--){
      f = s * e[i2 - 1];
      b = c * e[i2 - 1];
      slartg_(g, f, c, s, r);
      if (i2 != m - 1) e[i2] = r;
      g = d[i2] - p;
      r = (d[i2 - 1] - g) * s + 2.0f * c * b;
      p = s * r;
      d[i2] = g + p;
      g = c * r - b;
      csave[i2 - l] = c; ssave[i2 - l] = -s;
    }
    {
      int mmc = m - l + 1;
      for (int j2 = mmc - 1; j2 >= 1; j2--){
        float cj = csave[j2 - 1], sj = ssave[j2 - 1];
        if (cj != 1.0f || sj != 0.0f){
          for (int i2 = 0; i2 < 3; i2++){
            float temp = z[i2][(l - 1) + j2];
            z[i2][(l - 1) + j2]     = cj * temp - sj * z[i2][(l - 1) + j2 - 1];
            z[i2][(l - 1) + j2 - 1] = sj * temp + cj * z[i2][(l - 1) + j2 - 1];
          }
        }
      }
    }
    d[l - 1] -= p;
    e[l - 1] = g;
    goto L40;
L80:
    d[l - 1] = p;
    l++;
    if (l <= lend) goto L40;
    goto L140;
  } else {
    // QR
L90:
    if (l != lend){
      for (m = l; m >= lend + 1; m--){
        float tst = e[m - 2] * e[m - 2];
        if (tst <= (eps2 * fabsf(d[m - 1])) * fabsf(d[m - 2]) + safmin) goto L110;
      }
    }
    m = lend;
L110:
    if (m > lend) e[m - 2] = 0.0f;
    p = d[l - 1];
    if (m == l) goto L130;
    if (m == l - 1){
      float rt1, rt2;
      slaev2_(d[l - 2], e[l - 2], d[l - 1], rt1, rt2, c, s);
      for (int i2 = 0; i2 < 3; i2++){
        float temp = z[i2][l - 1];
        z[i2][l - 1] = c * temp - s * z[i2][l - 2];
        z[i2][l - 2] = s * temp + c * z[i2][l - 2];
      }
      d[l - 2] = rt1; d[l - 1] = rt2; e[l - 2] = 0.0f;
      l -= 2;
      if (l >= lend) goto L90;
      goto L140;
    }
    if (jtot == nmaxit) goto L140;
    jtot++;
    g = (d[l - 2] - p) / (2.0f * e[l - 2]);
    r = lapy2f(g, 1.0f);
    g = d[m - 1] - p + e[l - 2] / (g + f_signf(r, g));
    s = 1.0f; c = 1.0f; p = 0.0f;
    for (int i2 = m; i2 <= l - 1; i2++){
      f = s * e[i2 - 1];
      b = c * e[i2 - 1];
      slartg_(g, f, c, s, r);
      if (i2 != m) e[i2 - 2] = r;
      g = d[i2 - 1] - p;
      r = (d[i2] - g) * s + 2.0f * c * b;
      p = s * r;
      d[i2 - 1] = g + p;
      g = c * r - b;
      csave[i2 - m] = c; ssave[i2 - m] = s;
    }
    {
      int cnt = l - m + 1;
      for (int j2 = 1; j2 <= cnt - 1; j2++){
        float cj = csave[j2 - 1], sj = ssave[j2 - 1];
        if (cj != 1.0f || sj != 0.0f){
          for (int i2 = 0; i2 < 3; i2++){
            float temp = z[i2][(m - 1) + j2];
            z[i2][(m - 1) + j2]     = cj * temp - sj * z[i2][(m - 1) + j2 - 1];
            z[i2][(m - 1) + j2 - 1] = sj * temp + cj * z[i2][(m - 1) + j2 - 1];
          }
        }
      }
    }
    d[l - 1] -= p;
    e[l - 2] = g;
    goto L90;
L130:
    d[l - 1] = p;
    l--;
    if (l >= lend) goto L90;
    goto L140;
  }
L140:
  if (jtot < nmaxit) goto L10;
  goto L190;
L160:
  for (int ii = 2; ii <= n; ii++){
    int i2 = ii - 1, k2 = i2;
    float pp = d[i2 - 1];
    for (int j2 = ii; j2 <= n; j2++){
      if (d[j2 - 1] < pp){ k2 = j2; pp = d[j2 - 1]; }
    }
    if (k2 != i2){
      d[k2 - 1] = d[i2 - 1]; d[i2 - 1] = pp;
      for (int r2 = 0; r2 < 3; r2++){
        float tt = z[r2][i2 - 1]; z[r2][i2 - 1] = z[r2][k2 - 1]; z[r2][k2 - 1] = tt;
      }
    }
  }
L190: ;
}

__device__ void eigh3_smallest_f32(const float A6[6], float zout[3]){
#pragma clang fp contract(off)
  float a00 = A6[0], a10 = A6[1], a20 = A6[2], a11 = A6[3], a21 = A6[4], a22 = A6[5];
  float d[3], e[2], tau1 = 0.0f, v2 = 0.0f;
  float xnorm = fabsf(a20);
  if (xnorm == 0.0f){
    tau1 = 0.0f;
    d[0] = a00; d[1] = a11; d[2] = a22; e[0] = a10; e[1] = a21;
  } else {
    float alpha = a10;
    float beta = -f_signf(lapy2f(alpha, xnorm), alpha);
    tau1 = (beta - alpha) / beta;
    float rsc = 1.0f / (alpha - beta);
    v2 = a20 * rsc;
    float y1 = tau1 * a11 + tau1 * (a21 * v2);
    float y2 = tau1 * a21 + (tau1 * v2) * a22;
    float dotv = y1 + y2 * v2;
    float al = (-0.5f * tau1) * dotv;
    float w1 = y1 + al;
    float w2 = y2 + al * v2;
    d[0] = a00;
    d[1] = (a11 + (-w1)) + (w1 * (-1.0f));
    e[1] = (a21 + v2 * (-w1)) + (w2 * (-1.0f));
    d[2] = (a22 + v2 * (-w2)) + (w2 * (-v2));
    e[0] = beta;
  }
  float z[3][3];
  ssteqr3(d, e, z);
  if (tau1 != 0.0f){
    for (int j = 0; j < 3; j++){
      float wj = z[1][j] + z[2][j] * v2;
      float tmp = (-tau1) * wj;
      z[1][j] = z[1][j] + tmp;
      z[2][j] = z[2][j] + v2 * tmp;
    }
  }
  zout[0] = z[0][0]; zout[1] = z[1][0]; zout[2] = z[2][0];
}

// ===================== wave helpers =====================
__device__ __forceinline__ void wsync(){
  asm volatile("s_waitcnt lgkmcnt(0)" ::: "memory");
}
__device__ __forceinline__ unsigned int wscan_incl(unsigned int v, int lane){
  #pragma unroll
  for (int off = 1; off < 64; off <<= 1){
    unsigned int n = (unsigned int)__shfl_up((int)v, off, 64);
    if (lane >= off) v += n;
  }
  return v;
}
__device__ __forceinline__ unsigned int lanepos(unsigned long long bal){
  return __builtin_amdgcn_mbcnt_hi((unsigned int)(bal >> 32),
         __builtin_amdgcn_mbcnt_lo((unsigned int)bal, 0u));
}

// D bits per np formula (bit-identical to passing rounds)
#define DBITS(A_, B_, C_, OUT_) { \
  float dot_ = fmaf(vz, (C_), fmaf(vy, (B_), vx * (A_))); \
  float sqj_ = ((A_) * (A_) + (B_) * (B_)) + (C_) * (C_); \
  float d2_ = (sqi - 2.0f * dot_) + sqj_; \
  float D_ = sqrtf(fmaxf(d2_, 1e-12f)); \
  OUT_ = __float_as_uint(D_); }

// ===================== phase 1: wave-per-query =====================
__global__ __launch_bounds__(TPB, 6) void phase1_kernel(const float* __restrict__ verts,
                                                        float* __restrict__ normals,
                                                        unsigned short* __restrict__ idx_out)
{
#pragma clang fp contract(off)
  // region A per wave: hist[4][257] u32 (4112 B) overlaid later by cand[384] u64 (3072 B)
  __shared__ unsigned long long regionA[WPB][514];
  // region B per wave: skey[128] u64 (1 KiB) then nb float4[128] (2 KiB)
  __shared__ float4 regionB[WPB][KNN];

  const int t    = threadIdx.x;
  const int w    = t >> 6;
  const int lane = t & 63;
  const int gq   = blockIdx.x * WPB + w;
  const int smp  = gq >> 13;
  const int i    = gq & (NPTS - 1);
  const float* V = verts + (size_t)smp * NPTS * 3;

  unsigned int* hist = (unsigned int*)&regionA[w][0];          // 4*257 u32
  unsigned long long* cand = &regionA[w][0];                   // 384 u64
  unsigned long long* skey = (unsigned long long*)&regionB[w][0]; // 128 u64
  float4* nbf = &regionB[w][0];                                // 128 float4

  const float vx = V[3 * i + 0], vy = V[3 * i + 1], vz = V[3 * i + 2];
  const float sqi = (vx * vx + vy * vy) + vz * vz;

  // ---- adaptive radix select (same semantics as passing rounds) ----
  unsigned int prefix = 0u, kt = KNN, cnt = 0u;
  int stop_shift = 0;
  const int hcopy = (lane & 3) * 257;
  for (int level = 0; level < 4; level++){
    const int shift = 24 - 8 * level;
    for (int z2 = lane; z2 < 1028; z2 += 64) hist[z2] = 0u;
    wsync();
    for (int k = 0; k < NPTS / 256; k++){
      const int j0 = k * 256 + lane * 4;
      const float4* Vp = (const float4*)(V + 3 * j0);
      float4 fa = Vp[0], fb = Vp[1], fc = Vp[2];
      float px[4] = {fa.x, fa.w, fb.z, fc.y};
      float py[4] = {fa.y, fb.x, fb.w, fc.z};
      float pz[4] = {fa.z, fb.y, fc.x, fc.w};
      #pragma unroll
      for (int s = 0; s < 4; s++){
        unsigned int bits; DBITS(px[s], py[s], pz[s], bits);
        if (level == 0 || (bits >> (shift + 8)) == (prefix >> (shift + 8)))
          atomicAdd(&hist[hcopy + ((bits >> shift) & 255u)], 1u);
      }
    }
    wsync();
    unsigned int h0 = hist[lane]        + hist[257 + lane]        + hist[514 + lane]        + hist[771 + lane];
    unsigned int h1 = hist[64 + lane]   + hist[257 + 64 + lane]   + hist[514 + 64 + lane]   + hist[771 + 64 + lane];
    unsigned int h2 = hist[128 + lane]  + hist[257 + 128 + lane]  + hist[514 + 128 + lane]  + hist[771 + 128 + lane];
    unsigned int h3 = hist[192 + lane]  + hist[257 + 192 + lane]  + hist[514 + 192 + lane]  + hist[771 + 192 + lane];
    unsigned int s0 = wscan_incl(h0, lane);
    unsigned int s1 = wscan_incl(h1, lane);
    unsigned int s2 = wscan_incl(h2, lane);
    unsigned int s3 = wscan_incl(h3, lane);
    unsigned int tot0 = (unsigned int)__shfl((int)s0, 63, 64);
    unsigned int tot1 = (unsigned int)__shfl((int)s1, 63, 64);
    unsigned int tot2 = (unsigned int)__shfl((int)s2, 63, 64);
    unsigned int i0 = s0;
    unsigned int i1 = s1 + tot0;
    unsigned int i2 = s2 + tot0 + tot1;
    unsigned int i3 = s3 + tot0 + tot1 + tot2;
    unsigned int selb = 0xffffffffu, nkt = 0u, ncnt = 0u;
    if (h0 > 0u && (i0 - h0) < kt && kt <= i0){ selb = (unsigned)lane;        nkt = kt - (i0 - h0); ncnt = h0; }
    if (h1 > 0u && (i1 - h1) < kt && kt <= i1){ selb = (unsigned)lane + 64u;  nkt = kt - (i1 - h1); ncnt = h1; }
    if (h2 > 0u && (i2 - h2) < kt && kt <= i2){ selb = (unsigned)lane + 128u; nkt = kt - (i2 - h2); ncnt = h2; }
    if (h3 > 0u && (i3 - h3) < kt && kt <= i3){ selb = (unsigned)lane + 192u; nkt = kt - (i3 - h3); ncnt = h3; }
    unsigned long long bal = __ballot(selb != 0xffffffffu);
    int src = (int)(__ffsll((long long)bal) - 1);
    selb = (unsigned int)__shfl((int)selb, src, 64);
    nkt  = (unsigned int)__shfl((int)nkt,  src, 64);
    ncnt = (unsigned int)__shfl((int)ncnt, src, 64);
    prefix = prefix | (selb << shift);
    kt = nkt; cnt = ncnt; stop_shift = shift;
    if (cnt <= 256u) break;
  }

  // ---- gather candidates (fill order irrelevant: ranked by value below) ----
  const unsigned int P = prefix >> stop_shift;
  unsigned int base = 0u;
  for (int k = 0; k < NPTS / 256; k++){
    const int j0 = k * 256 + lane * 4;
    const float4* Vp = (const float4*)(V + 3 * j0);
    float4 fa = Vp[0], fb = Vp[1], fc = Vp[2];
    float px[4] = {fa.x, fa.w, fb.z, fc.y};
    float py[4] = {fa.y, fb.x, fb.w, fc.z};
    float pz[4] = {fa.z, fb.y, fc.x, fc.w};
    #pragma unroll
    for (int s = 0; s < 4; s++){
      unsigned int bits; DBITS(px[s], py[s], pz[s], bits);
      bool pred = ((bits >> stop_shift) <= P);
      unsigned long long bal = __ballot(pred);
      if (pred){
        unsigned int p = base + lanepos(bal);
        if (p < CANDCAP) cand[p] = (((unsigned long long)bits) << 13) | (unsigned long long)(j0 + s);
      }
      base += (unsigned int)__popcll(bal);
    }
  }
  wsync();
  unsigned int candN = base; if (candN > CANDCAP) candN = CANDCAP;

  // ---- rank sort -> exact np top_k order (D asc, idx asc) ----
  for (unsigned int c = lane; c < candN; c += 64){
    unsigned long long key = cand[c];
    unsigned int rank = 0u;
    #pragma unroll 4
    for (unsigned int jj = 0; jj < candN; jj++) rank += (cand[jj] < key) ? 1u : 0u;
    if (rank < KNN) skey[rank] = key;
  }
  wsync();

  // ---- read keys, then overwrite region with neighborhoods (float4) ----
  const float radius = __uint_as_float((unsigned int)(skey[KNN - 1] >> 13));
  unsigned long long k0 = skey[lane];
  unsigned long long k1 = skey[lane + 64];
  wsync();   // all skey reads complete before nbf writes (same region)
  {
    int j0 = (int)(k0 & 8191ULL);
    float a = V[3 * j0 + 0] - vx;
    float b = V[3 * j0 + 1] - vy;
    float c = V[3 * j0 + 2] - vz;
    float dd2 = (a * a + b * b) + c * c;
    nbf[lane] = make_float4(a, b, c, radius - sqrtf(fmaxf(dd2, 1e-12f)));
    idx_out[(size_t)gq * KNN + lane] = (unsigned short)j0;
  }
  {
    int j1 = (int)(k1 & 8191ULL);
    float a = V[3 * j1 + 0] - vx;
    float b = V[3 * j1 + 1] - vy;
    float c = V[3 * j1 + 2] - vz;
    float dd2 = (a * a + b * b) + c * c;
    nbf[lane + 64] = make_float4(a, b, c, radius - sqrtf(fmaxf(dd2, 1e-12f)));
    idx_out[(size_t)gq * KNN + 64 + lane] = (unsigned short)j1;
  }
  wsync();

  // ---- covariance: 6 lanes run the IDENTICAL sequential chains; lane 6 = wsum ----
  float acc = 0.0f;
  if (lane < 6){
    #pragma unroll 4
    for (int k = 0; k < KNN; k++){
      float4 nb4 = nbf[k];
      float wn = nb4.w, x = nb4.x, y = nb4.y, zc = nb4.z;
      float u = (lane == 0) ? x : ((lane == 1 || lane == 3) ? y : zc);
      float v = (lane < 3) ? x : ((lane < 5) ? y : zc);
      acc += (wn * u) * v;    // c00,c10,c20,c11,c21,c22 for lane=0..5
    }
  } else if (lane == 6){
    float r8[8];
    for (int q = 0; q < 8; q++) r8[q] = nbf[q].w;
    for (int k = 8; k < KNN; k += 8)
      for (int q = 0; q < 8; q++) r8[q] += nbf[k + q].w;
    acc = ((r8[0] + r8[1]) + (r8[2] + r8[3])) + ((r8[4] + r8[5]) + (r8[6] + r8[7]));
  }
  float c00 = __shfl(acc, 0, 64), c10 = __shfl(acc, 1, 64), c20 = __shfl(acc, 2, 64);
  float c11 = __shfl(acc, 3, 64), c21 = __shfl(acc, 4, 64), c22 = __shfl(acc, 5, 64);
  float wsum = __shfl(acc, 6, 64);

  // ---- eigh on all lanes redundantly (uniform -> no divergence) ----
  float A6[6];
  A6[0] = c00 / wsum; A6[1] = c10 / wsum; A6[2] = c20 / wsum;
  A6[3] = c11 / wsum; A6[4] = c21 / wsum; A6[5] = c22 / wsum;
  float zv[3];
  eigh3_smallest_f32(A6, zv);

  // ---- vote (exact formula/order), sign, write ----
  float4 q0 = nbf[lane], q1 = nbf[lane + 64];
  float zp0 = ((q0.x * zv[0]) + (q0.y * zv[1])) + (q0.z * zv[2]);
  float zp1 = ((q1.x * zv[0]) + (q1.y * zv[1])) + (q1.z * zv[2]);
  unsigned int votes = (unsigned int)__popcll(__ballot(zp0 >= 0.0f))
                     + (unsigned int)__popcll(__ballot(zp1 >= 0.0f));
  float sg = (votes >= (unsigned)(KNN - votes)) ? 1.0f : -1.0f;
  if (lane == 0){
    normals[(size_t)gq * 3 + 0] = sg * zv[0];
    normals[(size_t)gq * 3 + 1] = sg * zv[1];
    normals[(size_t)gq * 3 + 2] = sg * zv[2];
  }
}

// ===================== phase 2: wave-per-point average + normalize =====================
__global__ __launch_bounds__(TPB) void phase2_kernel(const float* __restrict__ normals,
                                                     const unsigned short* __restrict__ idx_in,
                                                     float* __restrict__ out)
{
#pragma clang fp contract(off)
  const int t    = threadIdx.x;
  const int w    = t >> 6;
  const int lane = t & 63;
  const int g    = blockIdx.x * WPB + w;
  const int smp  = g >> 13;
  const int base = smp << 13;
  const int j0 = (int)idx_in[(size_t)g * KNN + lane];
  const int j1 = (int)idx_in[(size_t)g * KNN + 64 + lane];
  const float* n0 = normals + (size_t)(base + j0) * 3;
  const float* n1 = normals + (size_t)(base + j1) * 3;
  float a0 = n0[0] + n1[0];
  float a1 = n0[1] + n1[1];
  float a2 = n0[2] + n1[2];
  #pragma unroll
  for (int off = 32; off > 0; off >>= 1){
    a0 += __shfl_down(a0, off, 64);
    a1 += __shfl_down(a1, off, 64);
    a2 += __shfl_down(a2, off, 64);
  }
  if (lane == 0){
    a0 /= 128.0f; a1 /= 128.0f; a2 /= 128.0f;
    float nrm = sqrtf(((a0 * a0) + (a1 * a1)) + (a2 * a2));
    out[(size_t)g * 3 + 0] = a0 / nrm;
    out[(size_t)g * 3 + 1] = a1 / nrm;
    out[(size_t)g * 3 + 2] = a2 / nrm;
  }
}

extern "C" void kernel_launch(void* const* d_in, const int* in_sizes, int n_in,
                              void* d_out, int out_size, void* d_ws, size_t ws_size,
                              hipStream_t stream){
  const float* verts = (const float*)d_in[0];
  float* out = (float*)d_out;
  const int total = in_sizes[0] / 3;   // 2 * 8192 points
  float* normals = (float*)d_ws;
  unsigned short* idxb = (unsigned short*)((char*)d_ws + (size_t)total * 3 * sizeof(float));
  phase1_kernel<<<dim3(total / WPB), dim3(TPB), 0, stream>>>(verts, normals, idxb);
  phase2_kernel<<<dim3(total / WPB), dim3(TPB), 0, stream>>>(normals, idxb, out);
}

// Round 9
// 277.525 us; speedup vs baseline: 7.6416x; 1.3443x over previous
//
#include <hip/hip_runtime.h>

#define NPTS 8192
#define KNN  128
#define TPB  256
#define WPB  4            // waves per block
#define CANDCAP 384       // max candidates: <=127 below-bin + <=256 in-bin

// ============ LAPACK-faithful 3x3 ssyevd (lower), FLOAT32, BLAS-ref op order ============
// UNCHANGED from the passing rounds (bit-exact path).

__device__ __forceinline__ float f_signf(float a, float b){ return copysignf(a, b); }

__device__ float lapy2f(float x, float y){
#pragma clang fp contract(off)
  float xa = fabsf(x), ya = fabsf(y);
  float w = fmaxf(xa, ya), zz = fminf(xa, ya);
  if (zz == 0.0f) return w;
  float t = zz / w;
  return w * sqrtf(1.0f + t * t);
}

__device__ void slartg_(float f, float g, float &c, float &s, float &r){
#pragma clang fp contract(off)
  const float safmin = 1.17549435e-38f;
  const float safmax = 8.5070592e37f;
  if (g == 0.0f){ c = 1.0f; s = 0.0f; r = f; }
  else if (f == 0.0f){ c = 0.0f; s = f_signf(1.0f, g); r = fabsf(g); }
  else {
    float f1 = fabsf(f), g1 = fabsf(g);
    float rtmin = sqrtf(safmin);
    float rtmax = sqrtf(safmax * 0.5f);
    if (f1 > rtmin && f1 < rtmax && g1 > rtmin && g1 < rtmax){
      float d = sqrtf(f * f + g * g);
      float p = 1.0f / d;
      c = f1 * p;
      s = g * f_signf(p, f);
      r = f_signf(d, f);
    } else {
      float u = fminf(safmax, fmaxf(safmin, fmaxf(f1, g1)));
      float uu = 1.0f / u;
      float fs = f * uu, gs = g * uu;
      float d = sqrtf(fs * fs + gs * gs);
      float p = 1.0f / d;
      c = fabsf(fs) * p;
      s = gs * f_signf(p, f);
      r = f_signf(d, f) * u;
    }
  }
}

__device__ void slaev2_(float a, float b, float cc, float &rt1, float &rt2,
                        float &cs1, float &sn1){
#pragma clang fp contract(off)
  float sm = a + cc;
  float df = a - cc;
  float adf = fabsf(df);
  float tb = b + b;
  float ab = fabsf(tb);
  float acmx, acmn;
  if (fabsf(a) > fabsf(cc)){ acmx = a; acmn = cc; } else { acmx = cc; acmn = a; }
  float rt;
  if (adf > ab){ float t = ab / adf; rt = adf * sqrtf(1.0f + t * t); }
  else if (adf < ab){ float t = adf / ab; rt = ab * sqrtf(1.0f + t * t); }
  else { rt = ab * sqrtf(2.0f); }
  int sgn1;
  if (sm < 0.0f){ rt1 = 0.5f * (sm - rt); sgn1 = -1; rt2 = (acmx / rt1) * acmn - (b / rt1) * b; }
  else if (sm > 0.0f){ rt1 = 0.5f * (sm + rt); sgn1 = 1; rt2 = (acmx / rt1) * acmn - (b / rt1) * b; }
  else { rt1 = 0.5f * rt; rt2 = -0.5f * rt; sgn1 = 1; }
  float cs; int sgn2;
  if (df >= 0.0f){ cs = df + rt; sgn2 = 1; }
  else { cs = df - rt; sgn2 = -1; }
  float acs = fabsf(cs);
  if (acs > ab){
    float ct = -tb / cs;
    sn1 = 1.0f / sqrtf(1.0f + ct * ct);
    cs1 = ct * sn1;
  } else {
    if (ab == 0.0f){ cs1 = 1.0f; sn1 = 0.0f; }
    else {
      float tn = -cs / tb;
      cs1 = 1.0f / sqrtf(1.0f + tn * tn);
      sn1 = tn * cs1;
    }
  }
  if (sgn1 == sgn2){ float tn = cs1; cs1 = -sn1; sn1 = tn; }
}

__device__ void ssteqr3(float *d, float *e, float z[3][3]){
#pragma clang fp contract(off)
  const float eps  = 5.9604645e-8f;
  const float eps2 = 3.5527137e-15f;
  const float safmin = 1.17549435e-38f;
  const int n = 3;
  for (int i = 0; i < 3; i++)
    for (int j = 0; j < 3; j++) z[i][j] = (i == j) ? 1.0f : 0.0f;
  const int nmaxit = n * 30;
  int jtot = 0;
  int l1 = 1;
  int l = 0, lsv = 0, lend = 0, lendsv = 0, m = 0;
  float p, g, r, c, s, f, b;
  float csave[2], ssave[2];
  int safety = 0;

L10:
  if (++safety > 64) goto L190;
  if (l1 > n) goto L160;
  if (l1 > 1) e[l1 - 2] = 0.0f;
  if (l1 <= n - 1){
    for (m = l1; m <= n - 1; m++){
      float tst = fabsf(e[m - 1]);
      if (tst == 0.0f) goto L30;
      if (tst <= (sqrtf(fabsf(d[m - 1])) * sqrtf(fabsf(d[m]))) * eps){ e[m - 1] = 0.0f; goto L30; }
    }
  }
  m = n;
L30:
  l = l1; lsv = l; lend = m; lendsv = lend; l1 = m + 1;
  if (lend == l) goto L10;
  {
    float anorm = fabsf(d[l - 1]);
    for (int q = l; q <= lend - 1; q++){
      anorm = fmaxf(anorm, fabsf(d[q]));
      anorm = fmaxf(anorm, fabsf(e[q - 1]));
    }
    if (anorm == 0.0f) goto L10;
  }
  if (fabsf(d[lend - 1]) < fabsf(d[l - 1])){ lend = lsv; l = lendsv; }
  if (lend > l){
    // QL
L40:
    if (l != lend){
      for (m = l; m <= lend - 1; m++){
        float tst = e[m - 1] * e[m - 1];
        if (tst <= (eps2 * fabsf(d[m - 1])) * fabsf(d[m]) + safmin) goto L60;
      }
    }
    m = lend;
L60:
    if (m < lend) e[m - 1] = 0.0f;
    p = d[l - 1];
    if (m == l) goto L80;
    if (m == l + 1){
      float rt1, rt2;
      slaev2_(d[l - 1], e[l - 1], d[l], rt1, rt2, c, s);
      for (int i2 = 0; i2 < 3; i2++){
        float temp = z[i2][l];
        z[i2][l]     = c * temp - s * z[i2][l - 1];
        z[i2][l - 1] = s * temp + c * z[i2][l - 1];
      }
      d[l - 1] = rt1; d[l] = rt2; e[l - 1] = 0.0f;
      l += 2;
      if (l <= lend) goto L40;
      goto L140;
    }
    if (jtot == nmaxit) goto L140;
    jtot++;
    g = (d[l] - p) / (2.0f * e[l - 1]);
    r = lapy2f(g, 1.0f);
    g = d[m - 1] - p + e[l - 1] / (g + f_signf(r, g));
    s = 1.0f; c = 1.0f; p = 0.0f;
    for (int i2 = m - 1; i2 >= l; i2--){
      f = s * e[i2 - 1];
      b = c * e[i2 - 1];
      slartg_(g, f, c, s, r);
      if (i2 != m - 1) e[i2] = r;
      g = d[i2] - p;
      r = (d[i2 - 1] - g) * s + 2.0f * c * b;
      p = s * r;
      d[i2] = g + p;
      g = c * r - b;
      csave[i2 - l] = c; ssave[i2 - l] = -s;
    }
    {
      int mmc = m - l + 1;
      for (int j2 = mmc - 1; j2 >= 1; j2--){
        float cj = csave[j2 - 1], sj = ssave[j2 - 1];
        if (cj != 1.0f || sj != 0.0f){
          for (int i2 = 0; i2 < 3; i2++){
            float temp = z[i2][(l - 1) + j2];
            z[i2][(l - 1) + j2]     = cj * temp - sj * z[i2][(l - 1) + j2 - 1];
            z[i2][(l - 1) + j2 - 1] = sj * temp + cj * z[i2][(l - 1) + j2 - 1];
          }
        }
      }
    }
    d[l - 1] -= p;
    e[l - 1] = g;
    goto L40;
L80:
    d[l - 1] = p;
    l++;
    if (l <= lend) goto L40;
    goto L140;
  } else {
    // QR
L90:
    if (l != lend){
      for (m = l; m >= lend + 1; m--){
        float tst = e[m - 2] * e[m - 2];
        if (tst <= (eps2 * fabsf(d[m - 1])) * fabsf(d[m - 2]) + safmin) goto L110;
      }
    }
    m = lend;
L110:
    if (m > lend) e[m - 2] = 0.0f;
    p = d[l - 1];
    if (m == l) goto L130;
    if (m == l - 1){
      float rt1, rt2;
      slaev2_(d[l - 2], e[l - 2], d[l - 1], rt1, rt2, c, s);
      for (int i2 = 0; i2 < 3; i2++){
        float temp = z[i2][l - 1];
        z[i2][l - 1] = c * temp - s * z[i2][l - 2];
        z[i2][l - 2] = s * temp + c * z[i2][l - 2];
      }
      d[l - 2] = rt1; d[l - 1] = rt2; e[l - 2] = 0.0f;
      l -= 2;
      if (l >= lend) goto L90;
      goto L140;
    }
    if (jtot == nmaxit) goto L140;
    jtot++;
    g = (d[l - 2] - p) / (2.0f * e[l - 2]);
    r = lapy2f(g, 1.0f);
    g = d[m - 1] - p + e[l - 2] / (g + f_signf(r, g));
    s = 1.0f; c = 1.0f; p = 0.0f;
    for (int i2 = m; i2 <= l - 1; i2++){
      f = s * e[i2 - 1];
      b = c * e[i2 - 1];
      slartg_(g, f, c, s, r);
      if (i2 != m) e[i2 - 2] = r;
      g = d[i2 - 1] - p;
      r = (d[i2] - g) * s + 2.0f * c * b;
      p = s * r;
      d[i2 - 1] = g + p;
      g = c * r - b;
      csave[i2 - m] = c; ssave[i2 - m] = s;
    }
    {
      int cnt = l - m + 1;
      for (int j2 = 1; j2 <= cnt - 1; j2++){
        float cj = csave[j2 - 1], sj = ssave[j2 - 1];
        if (cj != 1.0f || sj != 0.0f){
          for (int i2 = 0; i2 < 3; i2++){
            float temp = z[i2][(m - 1) + j2];
            z[i2][(m - 1) + j2]     = cj * temp - sj * z[i2][(m - 1) + j2 - 1];
            z[i2][(m - 1) + j2 - 1] = sj * temp + cj * z[i2][(m - 1) + j2 - 1];
          }
        }
      }
    }
    d[l - 1] -= p;
    e[l - 2] = g;
    goto L90;
L130:
    d[l - 1] = p;
    l--;
    if (l >= lend) goto L90;
    goto L140;
  }
L140:
  if (jtot < nmaxit) goto L10;
  goto L190;
L160:
  for (int ii = 2; ii <= n; ii++){
    int i2 = ii - 1, k2 = i2;
    float pp = d[i2 - 1];
    for (int j2 = ii; j2 <= n; j2++){
      if (d[j2 - 1] < pp){ k2 = j2; pp = d[j2 - 1]; }
    }
    if (k2 != i2){
      d[k2 - 1] = d[i2 - 1]; d[i2 - 1] = pp;
      for (int r2 = 0; r2 < 3; r2++){
        float tt = z[r2][i2 - 1]; z[r2][i2 - 1] = z[r2][k2 - 1]; z[r2][k2 - 1] = tt;
      }
    }
  }
L190: ;
}

__device__ void eigh3_smallest_f32(const float A6[6], float zout[3]){
#pragma clang fp contract(off)
  float a00 = A6[0], a10 = A6[1], a20 = A6[2], a11 = A6[3], a21 = A6[4], a22 = A6[5];
  float d[3], e[2], tau1 = 0.0f, v2 = 0.0f;
  float xnorm = fabsf(a20);
  if (xnorm == 0.0f){
    tau1 = 0.0f;
    d[0] = a00; d[1] = a11; d[2] = a22; e[0] = a10; e[1] = a21;
  } else {
    float alpha = a10;
    float beta = -f_signf(lapy2f(alpha, xnorm), alpha);
    tau1 = (beta - alpha) / beta;
    float rsc = 1.0f / (alpha - beta);
    v2 = a20 * rsc;
    float y1 = tau1 * a11 + tau1 * (a21 * v2);
    float y2 = tau1 * a21 + (tau1 * v2) * a22;
    float dotv = y1 + y2 * v2;
    float al = (-0.5f * tau1) * dotv;
    float w1 = y1 + al;
    float w2 = y2 + al * v2;
    d[0] = a00;
    d[1] = (a11 + (-w1)) + (w1 * (-1.0f));
    e[1] = (a21 + v2 * (-w1)) + (w2 * (-1.0f));
    d[2] = (a22 + v2 * (-w2)) + (w2 * (-v2));
    e[0] = beta;
  }
  float z[3][3];
  ssteqr3(d, e, z);
  if (tau1 != 0.0f){
    for (int j = 0; j < 3; j++){
      float wj = z[1][j] + z[2][j] * v2;
      float tmp = (-tau1) * wj;
      z[1][j] = z[1][j] + tmp;
      z[2][j] = z[2][j] + v2 * tmp;
    }
  }
  zout[0] = z[0][0]; zout[1] = z[1][0]; zout[2] = z[2][0];
}

// ===================== wave helpers =====================
__device__ __forceinline__ void wsync(){
  asm volatile("s_waitcnt lgkmcnt(0)" ::: "memory");
}
__device__ __forceinline__ unsigned int wscan_incl(unsigned int v, int lane){
  #pragma unroll
  for (int off = 1; off < 64; off <<= 1){
    unsigned int n = (unsigned int)__shfl_up((int)v, off, 64);
    if (lane >= off) v += n;
  }
  return v;
}
__device__ __forceinline__ unsigned int lanepos(unsigned long long bal){
  return __builtin_amdgcn_mbcnt_hi((unsigned int)(bal >> 32),
         __builtin_amdgcn_mbcnt_lo((unsigned int)bal, 0u));
}

// D bits per np formula (bit-identical to passing rounds)
#define DBITS(A_, B_, C_, OUT_) { \
  float dot_ = fmaf(vz, (C_), fmaf(vy, (B_), vx * (A_))); \
  float sqj_ = ((A_) * (A_) + (B_) * (B_)) + (C_) * (C_); \
  float d2_ = (sqi - 2.0f * dot_) + sqj_; \
  float D_ = sqrtf(fmaxf(d2_, 1e-12f)); \
  OUT_ = __float_as_uint(D_); }

// ===================== phase 1: wave-per-query =====================
// Radix digits on D bits: level0 = 12-bit bucket ((bits>>19)-1696, 512 bins:
// D >= sqrt(1e-12) -> exp >= 107; 512 bins cover exp in [106,138) i.e. D up to 2^11).
// Fallback levels at shifts 11, 3, 0 keep exactness for pathological ties.
__global__ __launch_bounds__(TPB, 8) void phase1_kernel(const float* __restrict__ verts,
                                                        float* __restrict__ normals,
                                                        unsigned short* __restrict__ idx_out)
{
#pragma clang fp contract(off)
  // region A per wave: cand[384] u64 (3072 B); hist (512 u32 = 2048 B) overlays its head
  __shared__ unsigned long long regionA[WPB][CANDCAP];
  // region B per wave: skey[128] u64 (1 KiB) then nb float4[128] (2 KiB)
  __shared__ float4 regionB[WPB][KNN];

  const int t    = threadIdx.x;
  const int w    = t >> 6;
  const int lane = t & 63;
  const int gq   = blockIdx.x * WPB + w;
  const int smp  = gq >> 13;
  const int i    = gq & (NPTS - 1);
  const float* V = verts + (size_t)smp * NPTS * 3;

  unsigned long long* cand = &regionA[w][0];
  unsigned int* hist = (unsigned int*)cand;                       // 512 u32
  unsigned long long* skey = (unsigned long long*)&regionB[w][0]; // 128 u64
  float4* nbf = &regionB[w][0];                                   // 128 float4

  const float vx = V[3 * i + 0], vy = V[3 * i + 1], vz = V[3 * i + 2];
  const float sqi = (vx * vx + vy * vy) + vz * vz;

  // ---- adaptive radix select on D bits (exact; same selection semantics) ----
  unsigned int prefix = 0u, kt = KNN, cnt = 0u;
  int shift = 19, pshift = 32, stop_shift = 19;
  for (int level = 0; level < 4; level++){
    #pragma unroll
    for (int z2 = 0; z2 < 8; z2++) hist[z2 * 64 + lane] = 0u;
    wsync();
    const unsigned int dmask = (unsigned int)((1 << (pshift - shift)) - 1);
    for (int k = 0; k < NPTS / 256; k++){
      const int j0 = k * 256 + lane * 4;
      const float4* Vp = (const float4*)(V + 3 * j0);
      float4 fa = Vp[0], fb = Vp[1], fc = Vp[2];
      float px[4] = {fa.x, fa.w, fb.z, fc.y};
      float py[4] = {fa.y, fb.x, fb.w, fc.z};
      float pz[4] = {fa.z, fb.y, fc.x, fc.w};
      #pragma unroll
      for (int s = 0; s < 4; s++){
        unsigned int bits; DBITS(px[s], py[s], pz[s], bits);
        if (level == 0){
          int v = (int)(bits >> 19) - 1696;
          unsigned int dig = (unsigned int)(v < 0 ? 0 : (v > 511 ? 511 : v));
          atomicAdd(&hist[dig], 1u);
        } else if ((bits >> pshift) == prefix){
          atomicAdd(&hist[(bits >> shift) & dmask], 1u);
        }
      }
    }
    wsync();
    // scan 512 bins (8 segments of 64)
    unsigned int hh[8], inc[8], tot[8];
    #pragma unroll
    for (int s = 0; s < 8; s++){
      hh[s] = hist[s * 64 + lane];
      inc[s] = wscan_incl(hh[s], lane);
      tot[s] = (unsigned int)__shfl((int)inc[s], 63, 64);
    }
    unsigned int selb = 0xffffffffu, nkt = 0u, ncnt = 0u, basep = 0u;
    #pragma unroll
    for (int s = 0; s < 8; s++){
      unsigned int gincl = inc[s] + basep;
      unsigned int gexcl = gincl - hh[s];
      if (hh[s] > 0u && gexcl < kt && kt <= gincl){
        selb = (unsigned int)(s * 64 + lane); nkt = kt - gexcl; ncnt = hh[s];
      }
      basep += tot[s];
    }
    unsigned long long bal = __ballot(selb != 0xffffffffu);
    int src = (int)(__ffsll((long long)bal) - 1);
    selb = (unsigned int)__shfl((int)selb, src, 64);
    nkt  = (unsigned int)__shfl((int)nkt,  src, 64);
    ncnt = (unsigned int)__shfl((int)ncnt, src, 64);
    prefix = (level == 0) ? (selb + 1696u) : ((prefix << (pshift - shift)) | selb);
    kt = nkt; cnt = ncnt; stop_shift = shift;
    if (cnt <= 256u) break;
    pshift = shift;
    shift = (shift == 19) ? 11 : ((shift == 11) ? 3 : 0);
  }

  // ---- gather candidates (fill order irrelevant: ranked by value below) ----
  unsigned int base = 0u;
  for (int k = 0; k < NPTS / 256; k++){
    const int j0 = k * 256 + lane * 4;
    const float4* Vp = (const float4*)(V + 3 * j0);
    float4 fa = Vp[0], fb = Vp[1], fc = Vp[2];
    float px[4] = {fa.x, fa.w, fb.z, fc.y};
    float py[4] = {fa.y, fb.x, fb.w, fc.z};
    float pz[4] = {fa.z, fb.y, fc.x, fc.w};
    #pragma unroll
    for (int s = 0; s < 4; s++){
      unsigned int bits; DBITS(px[s], py[s], pz[s], bits);
      bool pred = ((bits >> stop_shift) <= prefix);
      unsigned long long bal = __ballot(pred);
      if (pred){
        unsigned int p = base + lanepos(bal);
        if (p < CANDCAP) cand[p] = (((unsigned long long)bits) << 13) | (unsigned long long)(j0 + s);
      }
      base += (unsigned int)__popcll(bal);
    }
  }
  wsync();
  unsigned int candN = base; if (candN > CANDCAP) candN = CANDCAP;

  // ---- rank sort -> exact np top_k order (D asc, idx asc) ----
  for (unsigned int c = lane; c < candN; c += 64){
    unsigned long long key = cand[c];
    unsigned int rank = 0u;
    #pragma unroll 4
    for (unsigned int jj = 0; jj < candN; jj++) rank += (cand[jj] < key) ? 1u : 0u;
    if (rank < KNN) skey[rank] = key;
  }
  wsync();

  // ---- read keys, then overwrite region with neighborhoods (float4) ----
  const float radius = __uint_as_float((unsigned int)(skey[KNN - 1] >> 13));
  unsigned long long k0 = skey[lane];
  unsigned long long k1 = skey[lane + 64];
  wsync();   // all skey reads complete before nbf writes (same region)
  {
    int j0 = (int)(k0 & 8191ULL);
    float a = V[3 * j0 + 0] - vx;
    float b = V[3 * j0 + 1] - vy;
    float c = V[3 * j0 + 2] - vz;
    float dd2 = (a * a + b * b) + c * c;
    nbf[lane] = make_float4(a, b, c, radius - sqrtf(fmaxf(dd2, 1e-12f)));
    idx_out[(size_t)gq * KNN + lane] = (unsigned short)j0;
  }
  {
    int j1 = (int)(k1 & 8191ULL);
    float a = V[3 * j1 + 0] - vx;
    float b = V[3 * j1 + 1] - vy;
    float c = V[3 * j1 + 2] - vz;
    float dd2 = (a * a + b * b) + c * c;
    nbf[lane + 64] = make_float4(a, b, c, radius - sqrtf(fmaxf(dd2, 1e-12f)));
    idx_out[(size_t)gq * KNN + 64 + lane] = (unsigned short)j1;
  }
  wsync();

  // ---- covariance: 6 lanes run the IDENTICAL sequential chains; lane 6 = wsum ----
  float acc = 0.0f;
  if (lane < 6){
    #pragma unroll 4
    for (int k = 0; k < KNN; k++){
      float4 nb4 = nbf[k];
      float wn = nb4.w, x = nb4.x, y = nb4.y, zc = nb4.z;
      float u = (lane == 0) ? x : ((lane == 1 || lane == 3) ? y : zc);
      float v = (lane < 3) ? x : ((lane < 5) ? y : zc);
      acc += (wn * u) * v;    // c00,c10,c20,c11,c21,c22 for lane=0..5
    }
  } else if (lane == 6){
    float r8[8];
    for (int q = 0; q < 8; q++) r8[q] = nbf[q].w;
    for (int k = 8; k < KNN; k += 8)
      for (int q = 0; q < 8; q++) r8[q] += nbf[k + q].w;
    acc = ((r8[0] + r8[1]) + (r8[2] + r8[3])) + ((r8[4] + r8[5]) + (r8[6] + r8[7]));
  }
  float c00 = __shfl(acc, 0, 64), c10 = __shfl(acc, 1, 64), c20 = __shfl(acc, 2, 64);
  float c11 = __shfl(acc, 3, 64), c21 = __shfl(acc, 4, 64), c22 = __shfl(acc, 5, 64);
  float wsum = __shfl(acc, 6, 64);

  // ---- eigh on all lanes redundantly (uniform -> no divergence) ----
  float A6[6];
  A6[0] = c00 / wsum; A6[1] = c10 / wsum; A6[2] = c20 / wsum;
  A6[3] = c11 / wsum; A6[4] = c21 / wsum; A6[5] = c22 / wsum;
  float zv[3];
  eigh3_smallest_f32(A6, zv);

  // ---- vote (exact formula/order), sign, write ----
  float4 q0 = nbf[lane], q1 = nbf[lane + 64];
  float zp0 = ((q0.x * zv[0]) + (q0.y * zv[1])) + (q0.z * zv[2]);
  float zp1 = ((q1.x * zv[0]) + (q1.y * zv[1])) + (q1.z * zv[2]);
  unsigned int votes = (unsigned int)__popcll(__ballot(zp0 >= 0.0f))
                     + (unsigned int)__popcll(__ballot(zp1 >= 0.0f));
  float sg = (votes >= (unsigned)(KNN - votes)) ? 1.0f : -1.0f;
  if (lane == 0){
    normals[(size_t)gq * 3 + 0] = sg * zv[0];
    normals[(size_t)gq * 3 + 1] = sg * zv[1];
    normals[(size_t)gq * 3 + 2] = sg * zv[2];
  }
}

// ===================== phase 2: wave-per-point average + normalize =====================
__global__ __launch_bounds__(TPB) void phase2_kernel(const float* __restrict__ normals,
                                                     const unsigned short* __restrict__ idx_in,
                                                     float* __restrict__ out)
{
#pragma clang fp contract(off)
  const int t    = threadIdx.x;
  const int w    = t >> 6;
  const int lane = t & 63;
  const int g    = blockIdx.x * WPB + w;
  const int smp  = g >> 13;
  const int base = smp << 13;
  const int j0 = (int)idx_in[(size_t)g * KNN + lane];
  const int j1 = (int)idx_in[(size_t)g * KNN + 64 + lane];
  const float* n0 = normals + (size_t)(base + j0) * 3;
  const float* n1 = normals + (size_t)(base + j1) * 3;
  float a0 = n0[0] + n1[0];
  float a1 = n0[1] + n1[1];
  float a2 = n0[2] + n1[2];
  #pragma unroll
  for (int off = 32; off > 0; off >>= 1){
    a0 += __shfl_down(a0, off, 64);
    a1 += __shfl_down(a1, off, 64);
    a2 += __shfl_down(a2, off, 64);
  }
  if (lane == 0){
    a0 /= 128.0f; a1 /= 128.0f; a2 /= 128.0f;
    float nrm = sqrtf(((a0 * a0) + (a1 * a1)) + (a2 * a2));
    out[(size_t)g * 3 + 0] = a0 / nrm;
    out[(size_t)g * 3 + 1] = a1 / nrm;
    out[(size_t)g * 3 + 2] = a2 / nrm;
  }
}

extern "C" void kernel_launch(void* const* d_in, const int* in_sizes, int n_in,
                              void* d_out, int out_size, void* d_ws, size_t ws_size,
                              hipStream_t stream){
  const float* verts = (const float*)d_in[0];
  float* out = (float*)d_out;
  const int total = in_sizes[0] / 3;   // 2 * 8192 points
  float* normals = (float*)d_ws;
  unsigned short* idxb = (unsigned short*)((char*)d_ws + (size_t)total * 3 * sizeof(float));
  phase1_kernel<<<dim3(total / WPB), dim3(TPB), 0, stream>>>(verts, normals, idxb);
  phase2_kernel<<<dim3(total / WPB), dim3(TPB), 0, stream>>>(normals, idxb, out);
}

// Round 10
// 269.200 us; speedup vs baseline: 7.8779x; 1.0309x over previous
//
#include <hip/hip_runtime.h>

#define NPTS 8192
#define KNN  128
#define TPB  256
#define WPB  4            // waves per block
#define CANDCAP 384       // max candidates: <=127 below-bin + <=256 in-bin

// ============ LAPACK-faithful 3x3 ssyevd (lower), FLOAT32, BLAS-ref op order ============
// UNCHANGED from the passing rounds (bit-exact path).

__device__ __forceinline__ float f_signf(float a, float b){ return copysignf(a, b); }

__device__ float lapy2f(float x, float y){
#pragma clang fp contract(off)
  float xa = fabsf(x), ya = fabsf(y);
  float w = fmaxf(xa, ya), zz = fminf(xa, ya);
  if (zz == 0.0f) return w;
  float t = zz / w;
  return w * sqrtf(1.0f + t * t);
}

__device__ void slartg_(float f, float g, float &c, float &s, float &r){
#pragma clang fp contract(off)
  const float safmin = 1.17549435e-38f;
  const float safmax = 8.5070592e37f;
  if (g == 0.0f){ c = 1.0f; s = 0.0f; r = f; }
  else if (f == 0.0f){ c = 0.0f; s = f_signf(1.0f, g); r = fabsf(g); }
  else {
    float f1 = fabsf(f), g1 = fabsf(g);
    float rtmin = sqrtf(safmin);
    float rtmax = sqrtf(safmax * 0.5f);
    if (f1 > rtmin && f1 < rtmax && g1 > rtmin && g1 < rtmax){
      float d = sqrtf(f * f + g * g);
      float p = 1.0f / d;
      c = f1 * p;
      s = g * f_signf(p, f);
      r = f_signf(d, f);
    } else {
      float u = fminf(safmax, fmaxf(safmin, fmaxf(f1, g1)));
      float uu = 1.0f / u;
      float fs = f * uu, gs = g * uu;
      float d = sqrtf(fs * fs + gs * gs);
      float p = 1.0f / d;
      c = fabsf(fs) * p;
      s = gs * f_signf(p, f);
      r = f_signf(d, f) * u;
    }
  }
}

__device__ void slaev2_(float a, float b, float cc, float &rt1, float &rt2,
                        float &cs1, float &sn1){
#pragma clang fp contract(off)
  float sm = a + cc;
  float df = a - cc;
  float adf = fabsf(df);
  float tb = b + b;
  float ab = fabsf(tb);
  float acmx, acmn;
  if (fabsf(a) > fabsf(cc)){ acmx = a; acmn = cc; } else { acmx = cc; acmn = a; }
  float rt;
  if (adf > ab){ float t = ab / adf; rt = adf * sqrtf(1.0f + t * t); }
  else if (adf < ab){ float t = adf / ab; rt = ab * sqrtf(1.0f + t * t); }
  else { rt = ab * sqrtf(2.0f); }
  int sgn1;
  if (sm < 0.0f){ rt1 = 0.5f * (sm - rt); sgn1 = -1; rt2 = (acmx / rt1) * acmn - (b / rt1) * b; }
  else if (sm > 0.0f){ rt1 = 0.5f * (sm + rt); sgn1 = 1; rt2 = (acmx / rt1) * acmn - (b / rt1) * b; }
  else { rt1 = 0.5f * rt; rt2 = -0.5f * rt; sgn1 = 1; }
  float cs; int sgn2;
  if (df >= 0.0f){ cs = df + rt; sgn2 = 1; }
  else { cs = df - rt; sgn2 = -1; }
  float acs = fabsf(cs);
  if (acs > ab){
    float ct = -tb / cs;
    sn1 = 1.0f / sqrtf(1.0f + ct * ct);
    cs1 = ct * sn1;
  } else {
    if (ab == 0.0f){ cs1 = 1.0f; sn1 = 0.0f; }
    else {
      float tn = -cs / tb;
      cs1 = 1.0f / sqrtf(1.0f + tn * tn);
      sn1 = tn * cs1;
    }
  }
  if (sgn1 == sgn2){ float tn = cs1; cs1 = -sn1; sn1 = tn; }
}

__device__ void ssteqr3(float *d, float *e, float z[3][3]){
#pragma clang fp contract(off)
  const float eps  = 5.9604645e-8f;
  const float eps2 = 3.5527137e-15f;
  const float safmin = 1.17549435e-38f;
  const int n = 3;
  for (int i = 0; i < 3; i++)
    for (int j = 0; j < 3; j++) z[i][j] = (i == j) ? 1.0f : 0.0f;
  const int nmaxit = n * 30;
  int jtot = 0;
  int l1 = 1;
  int l = 0, lsv = 0, lend = 0, lendsv = 0, m = 0;
  float p, g, r, c, s, f, b;
  float csave[2], ssave[2];
  int safety = 0;

L10:
  if (++safety > 64) goto L190;
  if (l1 > n) goto L160;
  if (l1 > 1) e[l1 - 2] = 0.0f;
  if (l1 <= n - 1){
    for (m = l1; m <= n - 1; m++){
      float tst = fabsf(e[m - 1]);
      if (tst == 0.0f) goto L30;
      if (tst <= (sqrtf(fabsf(d[m - 1])) * sqrtf(fabsf(d[m]))) * eps){ e[m - 1] = 0.0f; goto L30; }
    }
  }
  m = n;
L30:
  l = l1; lsv = l; lend = m; lendsv = lend; l1 = m + 1;
  if (lend == l) goto L10;
  {
    float anorm = fabsf(d[l - 1]);
    for (int q = l; q <= lend - 1; q++){
      anorm = fmaxf(anorm, fabsf(d[q]));
      anorm = fmaxf(anorm, fabsf(e[q - 1]));
    }
    if (anorm == 0.0f) goto L10;
  }
  if (fabsf(d[lend - 1]) < fabsf(d[l - 1])){ lend = lsv; l = lendsv; }
  if (lend > l){
    // QL
L40:
    if (l != lend){
      for (m = l; m <= lend - 1; m++){
        float tst = e[m - 1] * e[m - 1];
        if (tst <= (eps2 * fabsf(d[m - 1])) * fabsf(d[m]) + safmin) goto L60;
      }
    }
    m = lend;
L60:
    if (m < lend) e[m - 1] = 0.0f;
    p = d[l - 1];
    if (m == l) goto L80;
    if (m == l + 1){
      float rt1, rt2;
      slaev2_(d[l - 1], e[l - 1], d[l], rt1, rt2, c, s);
      for (int i2 = 0; i2 < 3; i2++){
        float temp = z[i2][l];
        z[i2][l]     = c * temp - s * z[i2][l - 1];
        z[i2][l - 1] = s * temp + c * z[i2][l - 1];
      }
      d[l - 1] = rt1; d[l] = rt2; e[l - 1] = 0.0f;
      l += 2;
      if (l <= lend) goto L40;
      goto L140;
    }
    if (jtot == nmaxit) goto L140;
    jtot++;
    g = (d[l] - p) / (2.0f * e[l - 1]);
    r = lapy2f(g, 1.0f);
    g = d[m - 1] - p + e[l - 1] / (g + f_signf(r, g));
    s = 1.0f; c = 1.0f; p = 0.0f;
    for (int i2 = m - 1; i2 >= l; i2--){
      f = s * e[i2 - 1];
      b = c * e[i2 - 1];
      slartg_(g, f, c, s, r);
      if (i2 != m - 1) e[i2] = r;
      g = d[i2] - p;
      r = (d[i2 - 1] - g) * s + 2.0f * c * b;
      p = s * r;
      d[i2] = g + p;
      g = c * r - b;
      csave[i2 - l] = c; ssave[i2 - l] = -s;
    }
    {
      int mmc = m - l + 1;
      for (int j2 = mmc - 1; j2 >= 1; j2--){
        float cj = csave[j2 - 1], sj = ssave[j2 - 1];
        if (cj != 1.0f || sj != 0.0f){
          for (int i2 = 0; i2 < 3; i2++){
            float temp = z[i2][(l - 1) + j2];
            z[i2][(l - 1) + j2]     = cj * temp - sj * z[i2][(l - 1) + j2 - 1];
            z[i2][(l - 1) + j2 - 1] = sj * temp + cj * z[i2][(l - 1) + j2 - 1];
          }
        }
      }
    }
    d[l - 1] -= p;
    e[l - 1] = g;
    goto L40;
L80:
    d[l - 1] = p;
    l++;
    if (l <= lend) goto L40;
    goto L140;
  } else {
    // QR
L90:
    if (l != lend){
      for (m = l; m >= lend + 1; m--){
        float tst = e[m - 2] * e[m - 2];
        if (tst <= (eps2 * fabsf(d[m - 1])) * fabsf(d[m - 2]) + safmin) goto L110;
      }
    }
    m = lend;
L110:
    if (m > lend) e[m - 2] = 0.0f;
    p = d[l - 1];
    if (m == l) goto L130;
    if (m == l - 1){
      float rt1, rt2;
      slaev2_(d[l - 2], e[l - 2], d[l - 1], rt1, rt2, c, s);
      for (int i2 = 0; i2 < 3; i2++){
        float temp = z[i2][l - 1];
        z[i2][l - 1] = c * temp - s * z[i2][l - 2];
        z[i2][l - 2] = s * temp + c * z[i2][l - 2];
      }
      d[l - 2] = rt1; d[l - 1] = rt2; e[l - 2] = 0.0f;
      l -= 2;
      if (l >= lend) goto L90;
      goto L140;
    }
    if (jtot == nmaxit) goto L140;
    jtot++;
    g = (d[l - 2] - p) / (2.0f * e[l - 2]);
    r = lapy2f(g, 1.0f);
    g = d[m - 1] - p + e[l - 2] / (g + f_signf(r, g));
    s = 1.0f; c = 1.0f; p = 0.0f;
    for (int i2 = m; i2 <= l - 1; i2++){
      f = s * e[i2 - 1];
      b = c * e[i2 - 1];
      slartg_(g, f, c, s, r);
      if (i2 != m) e[i2 - 2] = r;
      g = d[i2 - 1] - p;
      r = (d[i2] - g) * s + 2.0f * c * b;
      p = s * r;
      d[i2 - 1] = g + p;
      g = c * r - b;
      csave[i2 - m] = c; ssave[i2 - m] = s;
    }
    {
      int cnt = l - m + 1;
      for (int j2 = 1; j2 <= cnt - 1; j2++){
        float cj = csave[j2 - 1], sj = ssave[j2 - 1];
        if (cj != 1.0f || sj != 0.0f){
          for (int i2 = 0; i2 < 3; i2++){
            float temp = z[i2][(m - 1) + j2];
            z[i2][(m - 1) + j2]     = cj * temp - sj * z[i2][(m - 1) + j2 - 1];
            z[i2][(m - 1) + j2 - 1] = sj * temp + cj * z[i2][(m - 1) + j2 - 1];
          }
        }
      }
    }
    d[l - 1] -= p;
    e[l - 2] = g;
    goto L90;
L130:
    d[l - 1] = p;
    l--;
    if (l >= lend) goto L90;
    goto L140;
  }
L140:
  if (jtot < nmaxit) goto L10;
  goto L190;
L160:
  for (int ii = 2; ii <= n; ii++){
    int i2 = ii - 1, k2 = i2;
    float pp = d[i2 - 1];
    for (int j2 = ii; j2 <= n; j2++){
      if (d[j2 - 1] < pp){ k2 = j2; pp = d[j2 - 1]; }
    }
    if (k2 != i2){
      d[k2 - 1] = d[i2 - 1]; d[i2 - 1] = pp;
      for (int r2 = 0; r2 < 3; r2++){
        float tt = z[r2][i2 - 1]; z[r2][i2 - 1] = z[r2][k2 - 1]; z[r2][k2 - 1] = tt;
      }
    }
  }
L190: ;
}

__device__ void eigh3_smallest_f32(const float A6[6], float zout[3]){
#pragma clang fp contract(off)
  float a00 = A6[0], a10 = A6[1], a20 = A6[2], a11 = A6[3], a21 = A6[4], a22 = A6[5];
  float d[3], e[2], tau1 = 0.0f, v2 = 0.0f;
  float xnorm = fabsf(a20);
  if (xnorm == 0.0f){
    tau1 = 0.0f;
    d[0] = a00; d[1] = a11; d[2] = a22; e[0] = a10; e[1] = a21;
  } else {
    float alpha = a10;
    float beta = -f_signf(lapy2f(alpha, xnorm), alpha);
    tau1 = (beta - alpha) / beta;
    float rsc = 1.0f / (alpha - beta);
    v2 = a20 * rsc;
    float y1 = tau1 * a11 + tau1 * (a21 * v2);
    float y2 = tau1 * a21 + (tau1 * v2) * a22;
    float dotv = y1 + y2 * v2;
    float al = (-0.5f * tau1) * dotv;
    float w1 = y1 + al;
    float w2 = y2 + al * v2;
    d[0] = a00;
    d[1] = (a11 + (-w1)) + (w1 * (-1.0f));
    e[1] = (a21 + v2 * (-w1)) + (w2 * (-1.0f));
    d[2] = (a22 + v2 * (-w2)) + (w2 * (-v2));
    e[0] = beta;
  }
  float z[3][3];
  ssteqr3(d, e, z);
  if (tau1 != 0.0f){
    for (int j = 0; j < 3; j++){
      float wj = z[1][j] + z[2][j] * v2;
      float tmp = (-tau1) * wj;
      z[1][j] = z[1][j] + tmp;
      z[2][j] = z[2][j] + v2 * tmp;
    }
  }
  zout[0] = z[0][0]; zout[1] = z[1][0]; zout[2] = z[2][0];
}

// ===================== wave helpers =====================
__device__ __forceinline__ void wsync(){
  asm volatile("s_waitcnt lgkmcnt(0)" ::: "memory");
}
__device__ __forceinline__ unsigned int wscan_incl(unsigned int v, int lane){
  #pragma unroll
  for (int off = 1; off < 64; off <<= 1){
    unsigned int n = (unsigned int)__shfl_up((int)v, off, 64);
    if (lane >= off) v += n;
  }
  return v;
}
__device__ __forceinline__ unsigned int lanepos(unsigned long long bal){
  return __builtin_amdgcn_mbcnt_hi((unsigned int)(bal >> 32),
         __builtin_amdgcn_mbcnt_lo((unsigned int)bal, 0u));
}

// D bits per np formula (bit-identical): sqj now PRELOADED (same f32 bits,
// precomputed once by sq_kernel with the identical expression).
#define DBITS(A_, B_, C_, SQJ_, OUT_) { \
  float dot_ = fmaf(vz, (C_), fmaf(vy, (B_), vx * (A_))); \
  float d2_ = (sqi - 2.0f * dot_) + (SQJ_); \
  float D_ = sqrtf(fmaxf(d2_, 1e-12f)); \
  OUT_ = __float_as_uint(D_); }

// ===================== sq precompute: sq_j = (x*x + y*y) + z*z, bit-exact =====================
__global__ __launch_bounds__(256) void sq_kernel(const float* __restrict__ verts,
                                                 float* __restrict__ sqbuf, int total)
{
#pragma clang fp contract(off)
  int g = blockIdx.x * 256 + threadIdx.x;
  if (g < total){
    float a = verts[3 * g + 0], b = verts[3 * g + 1], c = verts[3 * g + 2];
    sqbuf[g] = (a * a + b * b) + c * c;
  }
}

// ===================== phase 1: wave-per-query =====================
// Radix digits on D bits: level0 = 12-bit bucket ((bits>>19)-1696, 512 bins).
// Fallback levels at shifts 11, 3, 0 keep exactness for pathological ties.
__global__ __launch_bounds__(TPB, 8) void phase1_kernel(const float* __restrict__ verts,
                                                        const float* __restrict__ sqbuf,
                                                        float* __restrict__ normals,
                                                        unsigned short* __restrict__ idx_out)
{
#pragma clang fp contract(off)
  __shared__ unsigned long long regionA[WPB][CANDCAP];
  __shared__ float4 regionB[WPB][KNN];

  const int t    = threadIdx.x;
  const int w    = t >> 6;
  const int lane = t & 63;
  const int gq   = blockIdx.x * WPB + w;
  const int smp  = gq >> 13;
  const int i    = gq & (NPTS - 1);
  const float* V  = verts + (size_t)smp * NPTS * 3;
  const float* SQ = sqbuf + (size_t)smp * NPTS;

  unsigned long long* cand = &regionA[w][0];
  unsigned int* hist = (unsigned int*)cand;                       // 512 u32
  unsigned long long* skey = (unsigned long long*)&regionB[w][0]; // 128 u64
  float4* nbf = &regionB[w][0];                                   // 128 float4

  const float vx = V[3 * i + 0], vy = V[3 * i + 1], vz = V[3 * i + 2];
  const float sqi = SQ[i];

  // ---- adaptive radix select on D bits (exact; same selection semantics) ----
  unsigned int prefix = 0u, kt = KNN, cnt = 0u;
  int shift = 19, pshift = 32, stop_shift = 19;
  for (int level = 0; level < 4; level++){
    #pragma unroll
    for (int z2 = 0; z2 < 8; z2++) hist[z2 * 64 + lane] = 0u;
    wsync();
    const unsigned int dmask = (unsigned int)((1 << (pshift - shift)) - 1);
    #pragma unroll 2
    for (int k = 0; k < NPTS / 256; k++){
      const int j0 = k * 256 + lane * 4;
      const float4* Vp = (const float4*)(V + 3 * j0);
      float4 fa = Vp[0], fb = Vp[1], fc = Vp[2];
      float4 sj = *(const float4*)(SQ + j0);
      float px[4] = {fa.x, fa.w, fb.z, fc.y};
      float py[4] = {fa.y, fb.x, fb.w, fc.z};
      float pz[4] = {fa.z, fb.y, fc.x, fc.w};
      float ps[4] = {sj.x, sj.y, sj.z, sj.w};
      #pragma unroll
      for (int s = 0; s < 4; s++){
        unsigned int bits; DBITS(px[s], py[s], pz[s], ps[s], bits);
        if (level == 0){
          int v = (int)(bits >> 19) - 1696;
          unsigned int dig = (unsigned int)(v < 0 ? 0 : (v > 511 ? 511 : v));
          atomicAdd(&hist[dig], 1u);
        } else if ((bits >> pshift) == prefix){
          atomicAdd(&hist[(bits >> shift) & dmask], 1u);
        }
      }
    }
    wsync();
    // scan 512 bins (8 segments of 64)
    unsigned int hh[8], inc[8], tot[8];
    #pragma unroll
    for (int s = 0; s < 8; s++){
      hh[s] = hist[s * 64 + lane];
      inc[s] = wscan_incl(hh[s], lane);
      tot[s] = (unsigned int)__shfl((int)inc[s], 63, 64);
    }
    unsigned int selb = 0xffffffffu, nkt = 0u, ncnt = 0u, basep = 0u;
    #pragma unroll
    for (int s = 0; s < 8; s++){
      unsigned int gincl = inc[s] + basep;
      unsigned int gexcl = gincl - hh[s];
      if (hh[s] > 0u && gexcl < kt && kt <= gincl){
        selb = (unsigned int)(s * 64 + lane); nkt = kt - gexcl; ncnt = hh[s];
      }
      basep += tot[s];
    }
    unsigned long long bal = __ballot(selb != 0xffffffffu);
    int src = (int)(__ffsll((long long)bal) - 1);
    selb = (unsigned int)__shfl((int)selb, src, 64);
    nkt  = (unsigned int)__shfl((int)nkt,  src, 64);
    ncnt = (unsigned int)__shfl((int)ncnt, src, 64);
    prefix = (level == 0) ? (selb + 1696u) : ((prefix << (pshift - shift)) | selb);
    kt = nkt; cnt = ncnt; stop_shift = shift;
    if (cnt <= 256u) break;
    pshift = shift;
    shift = (shift == 19) ? 11 : ((shift == 11) ? 3 : 0);
  }

  // ---- gather candidates (fill order irrelevant: ranked by value below) ----
  unsigned int base = 0u;
  #pragma unroll 2
  for (int k = 0; k < NPTS / 256; k++){
    const int j0 = k * 256 + lane * 4;
    const float4* Vp = (const float4*)(V + 3 * j0);
    float4 fa = Vp[0], fb = Vp[1], fc = Vp[2];
    float4 sj = *(const float4*)(SQ + j0);
    float px[4] = {fa.x, fa.w, fb.z, fc.y};
    float py[4] = {fa.y, fb.x, fb.w, fc.z};
    float pz[4] = {fa.z, fb.y, fc.x, fc.w};
    float ps[4] = {sj.x, sj.y, sj.z, sj.w};
    #pragma unroll
    for (int s = 0; s < 4; s++){
      unsigned int bits; DBITS(px[s], py[s], pz[s], ps[s], bits);
      bool pred = ((bits >> stop_shift) <= prefix);
      unsigned long long bal = __ballot(pred);
      if (pred){
        unsigned int p = base + lanepos(bal);
        if (p < CANDCAP) cand[p] = (((unsigned long long)bits) << 13) | (unsigned long long)(j0 + s);
      }
      base += (unsigned int)__popcll(bal);
    }
  }
  wsync();
  unsigned int candN = base; if (candN > CANDCAP) candN = CANDCAP;

  // ---- rank sort -> exact np top_k order (D asc, idx asc) ----
  for (unsigned int c = lane; c < candN; c += 64){
    unsigned long long key = cand[c];
    unsigned int rank = 0u;
    #pragma unroll 4
    for (unsigned int jj = 0; jj < candN; jj++) rank += (cand[jj] < key) ? 1u : 0u;
    if (rank < KNN) skey[rank] = key;
  }
  wsync();

  // ---- read keys, then overwrite region with neighborhoods (float4) ----
  const float radius = __uint_as_float((unsigned int)(skey[KNN - 1] >> 13));
  unsigned long long k0 = skey[lane];
  unsigned long long k1 = skey[lane + 64];
  wsync();   // all skey reads complete before nbf writes (same region)
  {
    int j0 = (int)(k0 & 8191ULL);
    float a = V[3 * j0 + 0] - vx;
    float b = V[3 * j0 + 1] - vy;
    float c = V[3 * j0 + 2] - vz;
    float dd2 = (a * a + b * b) + c * c;
    nbf[lane] = make_float4(a, b, c, radius - sqrtf(fmaxf(dd2, 1e-12f)));
    idx_out[(size_t)gq * KNN + lane] = (unsigned short)j0;
  }
  {
    int j1 = (int)(k1 & 8191ULL);
    float a = V[3 * j1 + 0] - vx;
    float b = V[3 * j1 + 1] - vy;
    float c = V[3 * j1 + 2] - vz;
    float dd2 = (a * a + b * b) + c * c;
    nbf[lane + 64] = make_float4(a, b, c, radius - sqrtf(fmaxf(dd2, 1e-12f)));
    idx_out[(size_t)gq * KNN + 64 + lane] = (unsigned short)j1;
  }
  wsync();

  // ---- covariance: 6 lanes run the IDENTICAL sequential chains; lane 6 = wsum ----
  float acc = 0.0f;
  if (lane < 6){
    #pragma unroll 4
    for (int k = 0; k < KNN; k++){
      float4 nb4 = nbf[k];
      float wn = nb4.w, x = nb4.x, y = nb4.y, zc = nb4.z;
      float u = (lane == 0) ? x : ((lane == 1 || lane == 3) ? y : zc);
      float v = (lane < 3) ? x : ((lane < 5) ? y : zc);
      acc += (wn * u) * v;    // c00,c10,c20,c11,c21,c22 for lane=0..5
    }
  } else if (lane == 6){
    float r8[8];
    for (int q = 0; q < 8; q++) r8[q] = nbf[q].w;
    for (int k = 8; k < KNN; k += 8)
      for (int q = 0; q < 8; q++) r8[q] += nbf[k + q].w;
    acc = ((r8[0] + r8[1]) + (r8[2] + r8[3])) + ((r8[4] + r8[5]) + (r8[6] + r8[7]));
  }
  float c00 = __shfl(acc, 0, 64), c10 = __shfl(acc, 1, 64), c20 = __shfl(acc, 2, 64);
  float c11 = __shfl(acc, 3, 64), c21 = __shfl(acc, 4, 64), c22 = __shfl(acc, 5, 64);
  float wsum = __shfl(acc, 6, 64);

  // ---- eigh on all lanes redundantly (uniform -> no divergence) ----
  float A6[6];
  A6[0] = c00 / wsum; A6[1] = c10 / wsum; A6[2] = c20 / wsum;
  A6[3] = c11 / wsum; A6[4] = c21 / wsum; A6[5] = c22 / wsum;
  float zv[3];
  eigh3_smallest_f32(A6, zv);

  // ---- vote (exact formula/order), sign, write ----
  float4 q0 = nbf[lane], q1 = nbf[lane + 64];
  float zp0 = ((q0.x * zv[0]) + (q0.y * zv[1])) + (q0.z * zv[2]);
  float zp1 = ((q1.x * zv[0]) + (q1.y * zv[1])) + (q1.z * zv[2]);
  unsigned int votes = (unsigned int)__popcll(__ballot(zp0 >= 0.0f))
                     + (unsigned int)__popcll(__ballot(zp1 >= 0.0f));
  float sg = (votes >= (unsigned)(KNN - votes)) ? 1.0f : -1.0f;
  if (lane == 0){
    normals[(size_t)gq * 3 + 0] = sg * zv[0];
    normals[(size_t)gq * 3 + 1] = sg * zv[1];
    normals[(size_t)gq * 3 + 2] = sg * zv[2];
  }
}

// ===================== phase 2: wave-per-point average + normalize =====================
__global__ __launch_bounds__(TPB) void phase2_kernel(const float* __restrict__ normals,
                                                     const unsigned short* __restrict__ idx_in,
                                                     float* __restrict__ out)
{
#pragma clang fp contract(off)
  const int t    = threadIdx.x;
  const int w    = t >> 6;
  const int lane = t & 63;
  const int g    = blockIdx.x * WPB + w;
  const int smp  = g >> 13;
  const int base = smp << 13;
  const int j0 = (int)idx_in[(size_t)g * KNN + lane];
  const int j1 = (int)idx_in[(size_t)g * KNN + 64 + lane];
  const float* n0 = normals + (size_t)(base + j0) * 3;
  const float* n1 = normals + (size_t)(base + j1) * 3;
  float a0 = n0[0] + n1[0];
  float a1 = n0[1] + n1[1];
  float a2 = n0[2] + n1[2];
  #pragma unroll
  for (int off = 32; off > 0; off >>= 1){
    a0 += __shfl_down(a0, off, 64);
    a1 += __shfl_down(a1, off, 64);
    a2 += __shfl_down(a2, off, 64);
  }
  if (lane == 0){
    a0 /= 128.0f; a1 /= 128.0f; a2 /= 128.0f;
    float nrm = sqrtf(((a0 * a0) + (a1 * a1)) + (a2 * a2));
    out[(size_t)g * 3 + 0] = a0 / nrm;
    out[(size_t)g * 3 + 1] = a1 / nrm;
    out[(size_t)g * 3 + 2] = a2 / nrm;
  }
}

extern "C" void kernel_launch(void* const* d_in, const int* in_sizes, int n_in,
                              void* d_out, int out_size, void* d_ws, size_t ws_size,
                              hipStream_t stream){
  const float* verts = (const float*)d_in[0];
  float* out = (float*)d_out;
  const int total = in_sizes[0] / 3;   // 2 * 8192 points
  float* normals = (float*)d_ws;
  unsigned short* idxb = (unsigned short*)((char*)d_ws + (size_t)total * 3 * sizeof(float));
  float* sqbuf = (float*)((char*)d_ws + (size_t)total * 3 * sizeof(float)
                                       + (size_t)total * KNN * sizeof(unsigned short));
  sq_kernel<<<dim3((total + 255) / 256), dim3(256), 0, stream>>>(verts, sqbuf, total);
  phase1_kernel<<<dim3(total / WPB), dim3(TPB), 0, stream>>>(verts, sqbuf, normals, idxb);
  phase2_kernel<<<dim3(total / WPB), dim3(TPB), 0, stream>>>(normals, idxb, out);
}